// Round 15
// baseline (1068.832 us; speedup 1.0000x reference)
//
#include <hip/hip_runtime.h>

#define BB 4
#define TT 2048
#define CC 1024
#define HH 4
#define DD 256
#define MM (BB*TT)

#define EPSV 1e-5f
#define NEGBIG (-1e30f)
#define SCALEV 0.0625f   // 1/sqrt(256)

typedef unsigned short u16;
typedef unsigned int   u32;
typedef __bf16 bf16x8 __attribute__((ext_vector_type(8)));
typedef float  f32x4  __attribute__((ext_vector_type(4)));
typedef float  f32x16 __attribute__((ext_vector_type(16)));

typedef u32 __attribute__((address_space(1))) gu32;
typedef u32 __attribute__((address_space(3))) lu32;

__device__ __forceinline__ u16 f2bf(float f){
  u32 u = __builtin_bit_cast(u32, f);
  u32 r = (u + 0x7fffu + ((u >> 16) & 1u)) >> 16;
  return (u16)r;
}
__device__ __forceinline__ float bf2f(u16 h){
  u32 u = ((u32)h) << 16;
  return __builtin_bit_cast(float, u);
}
__device__ __forceinline__ void gload_lds16(const u16* g, u16* l){
  __builtin_amdgcn_global_load_lds((const gu32*)g, (lu32*)l, 16, 0, 0);
}
__device__ __forceinline__ u32 cvtpk_bf16(float lo, float hi){
  u32 r;
  asm("v_cvt_pk_bf16_f32 %0, %1, %2" : "=v"(r) : "v"(lo), "v"(hi));
  return r;
}

// ---------------- weight f32 -> bf16 ----------------
__global__ __launch_bounds__(256) void conv_w_kernel(
    const float* __restrict__ w0, const float* __restrict__ w1, const float* __restrict__ w2,
    const float* __restrict__ w3, const float* __restrict__ w4, const float* __restrict__ w5,
    u16* __restrict__ o0, u16* __restrict__ o1, u16* __restrict__ o2,
    u16* __restrict__ o3, u16* __restrict__ o4, u16* __restrict__ o5){
  const int i = (blockIdx.x * 256 + threadIdx.x) * 4;
  const float* wsrc[6] = {w0,w1,w2,w3,w4,w5};
  u16* odst[6] = {o0,o1,o2,o3,o4,o5};
#pragma unroll
  for (int k = 0; k < 6; ++k){
    float4 v = *(const float4*)(wsrc[k] + i);
    ushort4 p; p.x=f2bf(v.x); p.y=f2bf(v.y); p.z=f2bf(v.z); p.w=f2bf(v.w);
    *(ushort4*)(odst[k] + i) = p;
  }
}

// ---------------- channel LayerNorm over C per (b,t) row (f32 in, bf16 out) ----------------
__global__ __launch_bounds__(256) void ln_rows(const float* __restrict__ x,
    const float* __restrict__ g, const float* __restrict__ be, u16* __restrict__ out){
  const int row = blockIdx.x, tid = threadIdx.x;
  const float4 v = ((const float4*)(x + (size_t)row * CC))[tid];
  float s  = v.x + v.y + v.z + v.w;
  float ss = v.x*v.x + v.y*v.y + v.z*v.z + v.w*v.w;
  __shared__ float sb[8];
#pragma unroll
  for (int o = 1; o < 64; o <<= 1){ s += __shfl_xor(s, o); ss += __shfl_xor(ss, o); }
  const int wid = tid >> 6, lane = tid & 63;
  if (lane == 0){ sb[wid] = s; sb[4 + wid] = ss; }
  __syncthreads();
  s  = sb[0] + sb[1] + sb[2] + sb[3];
  ss = sb[4] + sb[5] + sb[6] + sb[7];
  const float mu = s * (1.0f / CC);
  const float rstd = rsqrtf(ss * (1.0f / CC) - mu * mu + EPSV);
  const float4 gg = ((const float4*)g)[tid];
  const float4 bb = ((const float4*)be)[tid];
  ushort4 p;
  p.x = f2bf((v.x - mu) * rstd * gg.x + bb.x);
  p.y = f2bf((v.y - mu) * rstd * gg.y + bb.y);
  p.z = f2bf((v.z - mu) * rstd * gg.z + bb.z);
  p.w = f2bf((v.w - mu) * rstd * gg.w + bb.w);
  *(ushort4*)(out + (size_t)row * CC + tid * 4) = p;
}

// ---------------- channel LayerNorm, bf16 in -> bf16 out ----------------
__global__ __launch_bounds__(256) void ln_rows_b2b(const u16* __restrict__ x,
    const float* __restrict__ g, const float* __restrict__ be, u16* __restrict__ out){
  const int row = blockIdx.x, tid = threadIdx.x;
  const ushort4 u = ((const ushort4*)(x + (size_t)row * CC))[tid];
  const float v0 = bf2f(u.x), v1 = bf2f(u.y), v2 = bf2f(u.z), v3 = bf2f(u.w);
  float s  = v0 + v1 + v2 + v3;
  float ss = v0*v0 + v1*v1 + v2*v2 + v3*v3;
  __shared__ float sb[8];
#pragma unroll
  for (int o = 1; o < 64; o <<= 1){ s += __shfl_xor(s, o); ss += __shfl_xor(ss, o); }
  const int wid = tid >> 6, lane = tid & 63;
  if (lane == 0){ sb[wid] = s; sb[4 + wid] = ss; }
  __syncthreads();
  s  = sb[0] + sb[1] + sb[2] + sb[3];
  ss = sb[4] + sb[5] + sb[6] + sb[7];
  const float mu = s * (1.0f / CC);
  const float rstd = rsqrtf(ss * (1.0f / CC) - mu * mu + EPSV);
  const float4 gg = ((const float4*)g)[tid];
  const float4 bb = ((const float4*)be)[tid];
  ushort4 p;
  p.x = f2bf((v0 - mu) * rstd * gg.x + bb.x);
  p.y = f2bf((v1 - mu) * rstd * gg.y + bb.y);
  p.z = f2bf((v2 - mu) * rstd * gg.z + bb.z);
  p.w = f2bf((v3 - mu) * rstd * gg.w + bb.w);
  *(ushort4*)(out + (size_t)row * CC + tid * 4) = p;
}

// ------------ fused q/k/v: dwconv3 (pad1) * mask -> LN -> bf16 (bf16 input h) ------------
__global__ __launch_bounds__(256) void qkv_pre(const u16* __restrict__ h,
    const int* __restrict__ mask,
    const float* __restrict__ qw, const float* __restrict__ kw, const float* __restrict__ vw,
    const float* __restrict__ qg, const float* __restrict__ qb2,
    const float* __restrict__ kg, const float* __restrict__ kb2,
    const float* __restrict__ vg, const float* __restrict__ vb2,
    u16* __restrict__ qn, u16* __restrict__ kn, u16* __restrict__ vn){
  const int row = blockIdx.x, tid = threadIdx.x;
  const int t = row & (TT - 1);
  const float mf = mask[row] ? 1.f : 0.f;
  ushort4 z4; z4.x = z4.y = z4.z = z4.w = 0;
  const ushort4 x0 = ((const ushort4*)(h + (size_t)row * CC))[tid];
  const ushort4 xm = (t > 0)      ? ((const ushort4*)(h + (size_t)(row - 1) * CC))[tid] : z4;
  const ushort4 xp = (t < TT - 1) ? ((const ushort4*)(h + (size_t)(row + 1) * CC))[tid] : z4;
  const int c = tid * 4;
  const float am[4] = {bf2f(xm.x), bf2f(xm.y), bf2f(xm.z), bf2f(xm.w)};
  const float a0[4] = {bf2f(x0.x), bf2f(x0.y), bf2f(x0.z), bf2f(x0.w)};
  const float ap[4] = {bf2f(xp.x), bf2f(xp.y), bf2f(xp.z), bf2f(xp.w)};
  float yq[4], yk[4], yv[4];
  float sq=0.f, ssq=0.f, sk=0.f, ssk=0.f, sv=0.f, ssv=0.f;
#pragma unroll
  for (int i = 0; i < 4; ++i){
    const float* qwp = qw + (c + i) * 3;
    const float* kwp = kw + (c + i) * 3;
    const float* vwp = vw + (c + i) * 3;
    const float q_ = (am[i]*qwp[0] + a0[i]*qwp[1] + ap[i]*qwp[2]) * mf;
    const float k_ = (am[i]*kwp[0] + a0[i]*kwp[1] + ap[i]*kwp[2]) * mf;
    const float v_ = (am[i]*vwp[0] + a0[i]*vwp[1] + ap[i]*vwp[2]) * mf;
    yq[i]=q_; yk[i]=k_; yv[i]=v_;
    sq+=q_; ssq+=q_*q_; sk+=k_; ssk+=k_*k_; sv+=v_; ssv+=v_*v_;
  }
  __shared__ float sb[24];
#pragma unroll
  for (int o = 1; o < 64; o <<= 1){
    sq += __shfl_xor(sq, o); ssq += __shfl_xor(ssq, o);
    sk += __shfl_xor(sk, o); ssk += __shfl_xor(ssk, o);
    sv += __shfl_xor(sv, o); ssv += __shfl_xor(ssv, o);
  }
  const int wid = tid >> 6, lane = tid & 63;
  if (lane == 0){
    sb[wid]=sq; sb[4+wid]=ssq; sb[8+wid]=sk; sb[12+wid]=ssk; sb[16+wid]=sv; sb[20+wid]=ssv;
  }
  __syncthreads();
  sq  = sb[0]+sb[1]+sb[2]+sb[3];    ssq = sb[4]+sb[5]+sb[6]+sb[7];
  sk  = sb[8]+sb[9]+sb[10]+sb[11];  ssk = sb[12]+sb[13]+sb[14]+sb[15];
  sv  = sb[16]+sb[17]+sb[18]+sb[19];ssv = sb[20]+sb[21]+sb[22]+sb[23];
  {
    const float mu = sq * (1.f/CC), rstd = rsqrtf(ssq*(1.f/CC) - mu*mu + EPSV);
    ushort4 p;
    p.x = f2bf((yq[0]-mu)*rstd*qg[c+0] + qb2[c+0]);
    p.y = f2bf((yq[1]-mu)*rstd*qg[c+1] + qb2[c+1]);
    p.z = f2bf((yq[2]-mu)*rstd*qg[c+2] + qb2[c+2]);
    p.w = f2bf((yq[3]-mu)*rstd*qg[c+3] + qb2[c+3]);
    *(ushort4*)(qn + (size_t)row * CC + c) = p;
  }
  {
    const float mu = sk * (1.f/CC), rstd = rsqrtf(ssk*(1.f/CC) - mu*mu + EPSV);
    ushort4 p;
    p.x = f2bf((yk[0]-mu)*rstd*kg[c+0] + kb2[c+0]);
    p.y = f2bf((yk[1]-mu)*rstd*kg[c+1] + kb2[c+1]);
    p.z = f2bf((yk[2]-mu)*rstd*kg[c+2] + kb2[c+2]);
    p.w = f2bf((yk[3]-mu)*rstd*kg[c+3] + kb2[c+3]);
    *(ushort4*)(kn + (size_t)row * CC + c) = p;
  }
  {
    const float mu = sv * (1.f/CC), rstd = rsqrtf(ssv*(1.f/CC) - mu*mu + EPSV);
    ushort4 p;
    p.x = f2bf((yv[0]-mu)*rstd*vg[c+0] + vb2[c+0]);
    p.y = f2bf((yv[1]-mu)*rstd*vg[c+1] + vb2[c+1]);
    p.z = f2bf((yv[2]-mu)*rstd*vg[c+2] + vb2[c+2]);
    p.w = f2bf((yv[3]-mu)*rstd*vg[c+3] + vb2[c+3]);
    *(ushort4*)(vn + (size_t)row * CC + c) = p;
  }
}

// ---------------- shared GEMM main loop v2: BK=64, double-buffered prefetch (T3 2-phase) ----------------
__device__ __forceinline__ void gemm_core(const u16* __restrict__ A, const u16* __restrict__ Bw,
    u16* As, u16* Bs, f32x4 acc[4][4], int bm, int bn, int tid){
  const int lane = tid & 63, wid = tid >> 6;
  const int wr = wid >> 1, wc = wid & 1;
  const int la = lane & 15, lg = lane >> 4;
  const int srow = tid >> 3;
  const int schunk = (tid & 7) ^ (srow & 7);
  const u16* gA = A  + (size_t)(bm * 128 + srow) * CC + schunk * 8;
  const u16* gB = Bw + (size_t)(bn * 128 + srow) * CC + schunk * 8;
  const int swz = (la & 7) << 4;
  auto stage = [&](int KT, int BUF){
    u16* dA = As + BUF * 8192 + tid * 8;
    u16* dB = Bs + BUF * 8192 + tid * 8;
#pragma unroll
    for (int i = 0; i < 4; ++i){
      gload_lds16(gA + (size_t)(i * 32) * CC + KT * 64, dA + i * 2048);
      gload_lds16(gB + (size_t)(i * 32) * CC + KT * 64, dB + i * 2048);
    }
  };
  stage(0, 0);
  __syncthreads();
  for (int kt = 0; kt < CC / 64; ++kt){
    const int cur = kt & 1;
    if (kt + 1 < CC / 64) stage(kt + 1, cur ^ 1);   // in flight across the compute phase
    const char* AsB = (const char*)(As + cur * 8192);
    const char* BsB = (const char*)(Bs + cur * 8192);
#pragma unroll
    for (int kk = 0; kk < 2; ++kk){
      bf16x8 af[4], bf[4];
      const int co = (kk * 64 + lg * 16) ^ swz;
#pragma unroll
      for (int mi = 0; mi < 4; ++mi)
        af[mi] = *(const bf16x8*)(AsB + (wr * 64 + mi * 16 + la) * 128 + co);
#pragma unroll
      for (int ni = 0; ni < 4; ++ni)
        bf[ni] = *(const bf16x8*)(BsB + (wc * 64 + ni * 16 + la) * 128 + co);
#pragma unroll
      for (int mi = 0; mi < 4; ++mi)
#pragma unroll
        for (int ni = 0; ni < 4; ++ni)
          acc[mi][ni] = __builtin_amdgcn_mfma_f32_16x16x32_bf16(af[mi], bf[ni], acc[mi][ni], 0, 0, 0);
    }
    __syncthreads();   // readers of buf[cur] done; stage into buf[cur^1] drained (vmcnt 0)
  }
}

// MODE 0: out bf16 (M,C).
// MODE 1: out bf16 = (acc+bias)*mask[m] + resid_f32[m,n]
// MODE 2: out f32  = acc + bias + resid_bf16[m,n]
template<int MODE>
__global__ __launch_bounds__(256, 2) void gemm_bt(
    const u16* __restrict__ A, const u16* __restrict__ Bw,
    const float* __restrict__ bias, void* __restrict__ out,
    const void* __restrict__ resid, const int* __restrict__ mask){
  __shared__ __align__(16) u16 As[2 * 8192];
  __shared__ __align__(16) u16 Bs[2 * 8192];
  const int tid = threadIdx.x, lane = tid & 63, wid = tid >> 6;
  const int wr = wid >> 1, wc = wid & 1;
  const int bm = blockIdx.x, bn = blockIdx.y;
  f32x4 acc[4][4];
#pragma unroll
  for (int i = 0; i < 4; ++i)
#pragma unroll
    for (int j = 0; j < 4; ++j) acc[i][j] = (f32x4){0.f, 0.f, 0.f, 0.f};
  gemm_core(A, Bw, As, Bs, acc, bm, bn, tid);
  const int la = lane & 15, lg = lane >> 4;
#pragma unroll
  for (int mi = 0; mi < 4; ++mi){
    const int mb = bm * 128 + wr * 64 + mi * 16 + lg * 4;
#pragma unroll
    for (int ni = 0; ni < 4; ++ni){
      const int n = bn * 128 + wc * 64 + ni * 16 + la;
      const float bz = bias[n];
      if (MODE == 0){
        u16* o = (u16*)out;
#pragma unroll
        for (int j = 0; j < 4; ++j) o[(size_t)(mb + j) * CC + n] = f2bf(acc[mi][ni][j] + bz);
      } else if (MODE == 1){
        u16* o = (u16*)out;
        const float* r = (const float*)resid;
#pragma unroll
        for (int j = 0; j < 4; ++j){
          const int m = mb + j;
          const float mf = mask[m] ? 1.f : 0.f;
          o[(size_t)m * CC + n] = f2bf((acc[mi][ni][j] + bz) * mf + r[(size_t)m * CC + n]);
        }
      } else {
        float* o = (float*)out;
        const u16* r = (const u16*)resid;
#pragma unroll
        for (int j = 0; j < 4; ++j){
          const int m = mb + j;
          o[(size_t)m * CC + n] = acc[mi][ni][j] + bz + bf2f(r[(size_t)m * CC + n]);
        }
      }
    }
  }
}

// fused q/k/v projection: z selects input/weight/bias/output; z==2 writes V transposed (B,H,D,T)
__global__ __launch_bounds__(256, 2) void gemm_qkv(
    const u16* __restrict__ qn, const u16* __restrict__ kn, const u16* __restrict__ vn,
    const u16* __restrict__ wq, const u16* __restrict__ wk, const u16* __restrict__ wv,
    const float* __restrict__ qb, const float* __restrict__ kb, const float* __restrict__ vb,
    u16* __restrict__ Qb, u16* __restrict__ Kb, u16* __restrict__ Vtb){
  __shared__ __align__(16) u16 As[2 * 8192];
  __shared__ __align__(16) u16 Bs[2 * 8192];
  const int z = blockIdx.z;
  const u16* A  = (z == 0) ? qn : (z == 1) ? kn : vn;
  const u16* Bw = (z == 0) ? wq : (z == 1) ? wk : wv;
  const float* bias = (z == 0) ? qb : (z == 1) ? kb : vb;
  const int tid = threadIdx.x, lane = tid & 63, wid = tid >> 6;
  const int wr = wid >> 1, wc = wid & 1;
  const int bm = blockIdx.x, bn = blockIdx.y;
  f32x4 acc[4][4];
#pragma unroll
  for (int i = 0; i < 4; ++i)
#pragma unroll
    for (int j = 0; j < 4; ++j) acc[i][j] = (f32x4){0.f, 0.f, 0.f, 0.f};
  gemm_core(A, Bw, As, Bs, acc, bm, bn, tid);
  const int la = lane & 15, lg = lane >> 4;
#pragma unroll
  for (int mi = 0; mi < 4; ++mi){
    const int mb = bm * 128 + wr * 64 + mi * 16 + lg * 4;
#pragma unroll
    for (int ni = 0; ni < 4; ++ni){
      const int n = bn * 128 + wc * 64 + ni * 16 + la;
      const float bz = bias[n];
      if (z < 2){
        u16* o = z ? Kb : Qb;
#pragma unroll
        for (int j = 0; j < 4; ++j) o[(size_t)(mb + j) * CC + n] = f2bf(acc[mi][ni][j] + bz);
      } else {
        const int bq = mb >> 11, tq = mb & (TT - 1);
        const int hq = n >> 8, dq = n & 255;
        ushort4 p;
        p.x = f2bf(acc[mi][ni][0] + bz); p.y = f2bf(acc[mi][ni][1] + bz);
        p.z = f2bf(acc[mi][ni][2] + bz); p.w = f2bf(acc[mi][ni][3] + bz);
        *(ushort4*)&Vtb[(size_t)((bq * HH + hq) * DD + dq) * TT + tq] = p;
      }
    }
  }
}

// ---------------- flash attention v11: kv-split=4, 4 blocks/CU (launch_bounds 256,4) ----------------
// Wave = 32 q; block = 4 waves = 128 q; KVB=32; LDS 32KB; unnormalized partials + stats.
// XCD x: h2 = x>>1; sp in {x&1, (x&1)+2}; all batches -> per-XCD work balanced.
// D layout (m74/m101): col=lane&31 (=q), row=(reg&3)+8*(reg>>2)+4*(lane>>5) (=k or d).
__global__ __launch_bounds__(256, 4) void flash_attn(
    const u16* __restrict__ Q, const u16* __restrict__ Kg,
    const u16* __restrict__ Vt, const int* __restrict__ mask,
    u16* __restrict__ Os0, u16* __restrict__ Os1,
    u16* __restrict__ Os2, u16* __restrict__ Os3, float2* __restrict__ stats){
  __shared__ __align__(16) u16 Ks[32 * 256];   // 16KB: row k 512B, chunk ^= (r&7)
  __shared__ __align__(16) u16 Vs[256 * 32];   // 16KB: row d 64B, chunk ^= ((d>>1)&3)
  const int Dn = blockIdx.x;
  const int xcd = Dn & 7, rest = Dn >> 3;      // rest 0..127
  const int h2 = xcd >> 1;
  const int sp = (xcd & 1) | ((rest >> 6) << 1);   // 0..3 kv-split quarter
  const int b = (rest >> 4) & 3, qt = rest & 15;
  const int bh = b * HH + h2;
  const int tid = threadIdx.x, lane = tid & 63, wid = tid >> 6;
  const int l31 = lane & 31, hi = lane >> 5;

  // ---- sequence length via two ballot rounds (prefix mask, len in [1024,2048]) ----
  const int* mrow = mask + b * TT;
  int len = 1024;
  {
    unsigned long long bal = __ballot(mrow[1024 + lane * 16] != 0);
    int ones = __popcll(bal);
    if (ones > 0){
      int lo = 1024 + (ones - 1) * 16;
      unsigned long long bal2 = __ballot(mrow[lo + (lane & 15)] != 0);
      len = lo + __popcll(bal2 & 0xFFFFull);
    }
  }
  const int nkt = (len + 31) >> 5;
  const int t0 = (sp * nkt) >> 2, t1 = ((sp + 1) * nkt) >> 2;

  // ---- Q fragments: lane holds q = q0 + l31, d = kd*16 + hi*8 .. +8 ----
  const int q0 = qt * 128 + wid * 32;
  bf16x8 qf[16];
  const u16* qrow = Q + (size_t)(b * TT + q0 + l31) * CC + h2 * DD + hi * 8;
#pragma unroll
  for (int kd = 0; kd < 16; ++kd) qf[kd] = *(const bf16x8*)(qrow + kd * 16);

  f32x16 acc[8];
#pragma unroll
  for (int i = 0; i < 8; ++i)
#pragma unroll
    for (int r = 0; r < 16; ++r) acc[i][r] = 0.f;
  float mrun = NEGBIG, lrun = 0.f;

  // ---- staging (pre-swizzled global source, linear LDS dest) ----
  const int krow = tid >> 5;
  const int kc = (tid & 31) ^ (krow & 7);
  const u16* ksrc = Kg + (size_t)(b * TT + krow) * CC + h2 * DD + kc * 8;
  const int vc = (tid & 3) ^ ((tid >> 3) & 3);
  const u16* vsrcb = Vt + (size_t)(bh * DD + (tid >> 2)) * TT + vc * 8;

#define STAGE_K(KT) { _Pragma("unroll") \
  for (int i = 0; i < 4; ++i) \
    gload_lds16(ksrc + (size_t)((KT) * 32 + i * 8) * CC, Ks + i * 2048 + tid * 8); }
#define STAGE_V(KT) { _Pragma("unroll") \
  for (int i = 0; i < 4; ++i) \
    gload_lds16(vsrcb + (size_t)(i * 64) * TT + (KT) * 32, Vs + i * 2048 + tid * 8); }

  STAGE_K(t0); STAGE_V(t0);
  __syncthreads();

  const char* KsB = (const char*)Ks;
  const char* VsB = (const char*)Vs;
  const int swk = (l31 & 7) << 4;          // K read byte-XOR (row = l31)
  const int swv = ((l31 >> 1) & 3) << 4;   // V read byte-XOR (row = dt*32+l31)
  const float sc2 = SCALEV * 1.44269504f;  // softmax in exp2 domain

  for (int kt = t0; kt < t1; ++kt){
    // ---- QK^T: S^T(32k x 32q) = K_tile * Q^T over 16 d-slices ----
    f32x16 s;
#pragma unroll
    for (int r = 0; r < 16; ++r) s[r] = 0.f;
#pragma unroll
    for (int kd = 0; kd < 16; ++kd){
      bf16x8 kf = *(const bf16x8*)(KsB + l31 * 512 + ((kd * 32 + hi * 16) ^ swk));
      s = __builtin_amdgcn_mfma_f32_32x32x16_bf16(kf, qf[kd], s, 0, 0, 0);
    }
    // scale + tail mask: lane reg r -> k = kt*32 + (r&3) + 8*(r>>2) + 4*hi
    if (kt * 32 + 32 <= len){
      s *= sc2;
    } else {
#pragma unroll
      for (int r = 0; r < 16; ++r){
        const int k = kt * 32 + (r & 3) + 8 * (r >> 2) + 4 * hi;
        s[r] = (k < len) ? s[r] * sc2 : NEGBIG;
      }
    }
    // ---- online softmax: q = l31 lane-local; k-halves split across lane^32 ----
    float tm = s[0];
#pragma unroll
    for (int r = 1; r < 16; ++r) tm = fmaxf(tm, s[r]);
    tm = fmaxf(tm, __shfl_xor(tm, 32));
    if (!__all(tm <= mrun + 12.0f)){   // defer-max
      const float mn = fmaxf(mrun, tm);
      const float al = __builtin_exp2f(mrun - mn);
      mrun = mn; lrun *= al;
#pragma unroll
      for (int i = 0; i < 8; ++i) acc[i] *= al;
    }
    float p[16];
    float ts = 0.f;
#pragma unroll
    for (int r = 0; r < 16; ++r){ p[r] = __builtin_exp2f(s[r] - mrun); ts += p[r]; }
    ts += __shfl_xor(ts, 32);
    lrun += ts;
    // ---- pack P to bf16 pairs and build PV B-frags via permlane32_swap ----
    u32 w0 = cvtpk_bf16(p[0],  p[1]),  w1 = cvtpk_bf16(p[2],  p[3]);
    u32 w2 = cvtpk_bf16(p[4],  p[5]),  w3 = cvtpk_bf16(p[6],  p[7]);
    u32 w4 = cvtpk_bf16(p[8],  p[9]),  w5 = cvtpk_bf16(p[10], p[11]);
    u32 w6 = cvtpk_bf16(p[12], p[13]), w7 = cvtpk_bf16(p[14], p[15]);
    asm("v_permlane32_swap_b32 %0, %1" : "+v"(w0), "+v"(w2));
    asm("v_permlane32_swap_b32 %0, %1" : "+v"(w1), "+v"(w3));
    asm("v_permlane32_swap_b32 %0, %1" : "+v"(w4), "+v"(w6));
    asm("v_permlane32_swap_b32 %0, %1" : "+v"(w5), "+v"(w7));
    u32 pb0u[4] = {w0, w1, w2, w3};   // k = hi*8 + 0..7
    u32 pb1u[4] = {w4, w5, w6, w7};   // k = 16 + hi*8 + 0..7
    bf16x8 pb0 = __builtin_bit_cast(bf16x8, *(uint4*)pb0u);
    bf16x8 pb1 = __builtin_bit_cast(bf16x8, *(uint4*)pb1u);
    __syncthreads();   // b1: Ks readers done; V(kt) stage drained
    if (kt + 1 < t1) STAGE_K(kt + 1);   // hides under PV, drained at b2
    // ---- PV: O^T(d x q) += V^T_tile * P^T ----
#pragma unroll
    for (int dt = 0; dt < 8; ++dt){
      const char* vr = VsB + (dt * 32 + l31) * 64;
      bf16x8 vf0 = *(const bf16x8*)(vr + ((hi * 16) ^ swv));
      acc[dt] = __builtin_amdgcn_mfma_f32_32x32x16_bf16(vf0, pb0, acc[dt], 0, 0, 0);
      bf16x8 vf1 = *(const bf16x8*)(vr + ((32 + hi * 16) ^ swv));
      acc[dt] = __builtin_amdgcn_mfma_f32_32x32x16_bf16(vf1, pb1, acc[dt], 0, 0, 0);
    }
    __syncthreads();   // b2: Vs readers done; K(kt+1) stage drained
    if (kt + 1 < t1) STAGE_V(kt + 1);   // drained at next b1
  }
  // ---- epilogue: unnormalized partial O + (m,l) stats ----
  u16* Os = (sp == 0) ? Os0 : (sp == 1) ? Os1 : (sp == 2) ? Os2 : Os3;
  u16* orow = Os + (size_t)(b * TT + q0 + l31) * CC + h2 * DD + hi * 4;
#pragma unroll
  for (int dt = 0; dt < 8; ++dt)
#pragma unroll
    for (int rg = 0; rg < 4; ++rg){
      ushort4 pk;
      pk.x = f2bf(acc[dt][rg * 4 + 0]); pk.y = f2bf(acc[dt][rg * 4 + 1]);
      pk.z = f2bf(acc[dt][rg * 4 + 2]); pk.w = f2bf(acc[dt][rg * 4 + 3]);
      *(ushort4*)(orow + dt * 32 + rg * 8) = pk;
    }
  if (lane < 32)
    stats[(size_t)((sp * 16 + bh) << 11) + q0 + l31] = make_float2(mrun, lrun);
#undef STAGE_K
#undef STAGE_V
}

// ---------------- combine the four kv-split partials ----------------
__global__ __launch_bounds__(256) void attn_combine(
    const u16* __restrict__ Os0, const u16* __restrict__ Os1,
    const u16* __restrict__ Os2, const u16* __restrict__ Os3,
    const float2* __restrict__ stats, u16* __restrict__ AO){
  const int row = blockIdx.x, tid = threadIdx.x;
  const int b = row >> 11, q = row & (TT - 1);
  const int h2 = tid >> 6;
  const int bh = b * HH + h2;
  const float2 s0 = stats[(size_t)(( 0 + bh) << 11) + q];
  const float2 s1 = stats[(size_t)((16 + bh) << 11) + q];
  const float2 s2 = stats[(size_t)((32 + bh) << 11) + q];
  const float2 s3 = stats[(size_t)((48 + bh) << 11) + q];
  const float m = fmaxf(fmaxf(s0.x, s1.x), fmaxf(s2.x, s3.x));
  const float e0 = __builtin_exp2f(s0.x - m), e1 = __builtin_exp2f(s1.x - m);
  const float e2 = __builtin_exp2f(s2.x - m), e3 = __builtin_exp2f(s3.x - m);
  const float l = s0.y * e0 + s1.y * e1 + s2.y * e2 + s3.y * e3;
  const float f0 = e0 / l, f1 = e1 / l, f2 = e2 / l, f3 = e3 / l;
  const size_t off = (size_t)row * CC + tid * 4;
  const ushort4 a0 = *(const ushort4*)(Os0 + off);
  const ushort4 a1 = *(const ushort4*)(Os1 + off);
  const ushort4 a2 = *(const ushort4*)(Os2 + off);
  const ushort4 a3 = *(const ushort4*)(Os3 + off);
  ushort4 o;
  o.x = f2bf(bf2f(a0.x) * f0 + bf2f(a1.x) * f1 + bf2f(a2.x) * f2 + bf2f(a3.x) * f3);
  o.y = f2bf(bf2f(a0.y) * f0 + bf2f(a1.y) * f1 + bf2f(a2.y) * f2 + bf2f(a3.y) * f3);
  o.z = f2bf(bf2f(a0.z) * f0 + bf2f(a1.z) * f1 + bf2f(a2.z) * f2 + bf2f(a3.z) * f3);
  o.w = f2bf(bf2f(a0.w) * f0 + bf2f(a1.w) * f1 + bf2f(a2.w) * f2 + bf2f(a3.w) * f3);
  *(ushort4*)(AO + off) = o;
}

// ---------------- dwconv(tc) + bias + exact GELU ----------------
__global__ __launch_bounds__(256) void tc_gelu(const u16* __restrict__ y2,
    const float* __restrict__ w, const float* __restrict__ bias, u16* __restrict__ y3){
  const int row = blockIdx.x, tid = threadIdx.x;
  const int t = row & (TT - 1);
  const int c = tid * 4;
  ushort4 z4; z4.x = z4.y = z4.z = z4.w = 0;
  const ushort4 u0 = *(const ushort4*)(y2 + (size_t)row * CC + c);
  const ushort4 um = (t > 0)      ? *(const ushort4*)(y2 + (size_t)(row - 1) * CC + c) : z4;
  const ushort4 up = (t < TT - 1) ? *(const ushort4*)(y2 + (size_t)(row + 1) * CC + c) : z4;
  const float am[4] = {bf2f(um.x), bf2f(um.y), bf2f(um.z), bf2f(um.w)};
  const float a0[4] = {bf2f(u0.x), bf2f(u0.y), bf2f(u0.z), bf2f(u0.w)};
  const float ap[4] = {bf2f(up.x), bf2f(up.y), bf2f(up.z), bf2f(up.w)};
  u16 pv[4];
#pragma unroll
  for (int i = 0; i < 4; ++i){
    const float* wp = w + (c + i) * 3;
    const float yv = am[i] * wp[0] + a0[i] * wp[1] + ap[i] * wp[2] + bias[c + i];
    const float ge = 0.5f * yv * (1.f + erff(yv * 0.7071067811865475f));
    pv[i] = f2bf(ge);
  }
  ushort4 p; p.x = pv[0]; p.y = pv[1]; p.z = pv[2]; p.w = pv[3];
  *(ushort4*)(y3 + (size_t)row * CC + c) = p;
}

extern "C" void kernel_launch(void* const* d_in, const int* in_sizes, int n_in,
                              void* d_out, int out_size, void* d_ws, size_t ws_size,
                              hipStream_t stream){
  const float* x     = (const float*)d_in[0];
  const int*   mask  = (const int*)d_in[1];
  const float* n1g   = (const float*)d_in[2];
  const float* n1b   = (const float*)d_in[3];
  const float* qconv = (const float*)d_in[4];
  const float* kconv = (const float*)d_in[5];
  const float* vconv = (const float*)d_in[6];
  const float* qg    = (const float*)d_in[7];
  const float* qbe   = (const float*)d_in[8];
  const float* kg    = (const float*)d_in[9];
  const float* kbe   = (const float*)d_in[10];
  const float* vg    = (const float*)d_in[11];
  const float* vbe   = (const float*)d_in[12];
  const float* q1w   = (const float*)d_in[13];
  const float* q1b   = (const float*)d_in[14];
  const float* k1w   = (const float*)d_in[15];
  const float* k1b   = (const float*)d_in[16];
  const float* v1w   = (const float*)d_in[17];
  const float* v1b   = (const float*)d_in[18];
  const float* pw    = (const float*)d_in[19];
  const float* pb    = (const float*)d_in[20];
  const float* n2g   = (const float*)d_in[21];
  const float* n2b   = (const float*)d_in[22];
  const float* l1w   = (const float*)d_in[23];
  const float* l1b   = (const float*)d_in[24];
  const float* tcw   = (const float*)d_in[25];
  const float* tcb   = (const float*)d_in[26];
  const float* l2w   = (const float*)d_in[27];
  const float* l2b   = (const float*)d_in[28];
  (void)in_sizes; (void)n_in; (void)out_size; (void)ws_size;

  char* ws = (char*)d_ws;
  const size_t MB = (size_t)1 << 20;
  u16* wq  = (u16*)(ws + 0 * MB);
  u16* wk  = (u16*)(ws + 2 * MB);
  u16* wv  = (u16*)(ws + 4 * MB);
  u16* wp2 = (u16*)(ws + 6 * MB);
  u16* wl1 = (u16*)(ws + 8 * MB);
  u16* wl2 = (u16*)(ws + 10 * MB);
  u16* hbuf = (u16*)(ws + 12 * MB);   // 16 MB bf16 LN1 output; dead after qkv_pre
  u16* Os2  = (u16*)(ws + 12 * MB);   // kv-split partial 2 (aliases hbuf; written by flash)
  u16* x2b  = (u16*)(ws + 12 * MB);   // 16 MB bf16 residual; written by gemm_bt<1> AFTER combine
  u16* Os3  = (u16*)(ws + 28 * MB);   // kv-split partial 3
  u16* qn  = (u16*)(ws + 44 * MB);
  u16* kn  = (u16*)(ws + 60 * MB);
  u16* vn  = (u16*)(ws + 76 * MB);
  u16* Qb  = (u16*)(ws + 92 * MB);
  u16* Kb  = (u16*)(ws + 108 * MB);
  u16* Vtb = (u16*)(ws + 124 * MB);
  float2* stats = (float2*)(ws + 140 * MB);   // 1 MB
  u16* AO  = qn;    // attnout  (qn dead after qkv GEMM)
  u16* Os0 = kn;    // kv-split partial 0 (kn dead after qkv GEMM)
  u16* Os1 = vn;    // kv-split partial 1 (vn dead after qkv GEMM)
  u16* y1  = kn;    // LN2 out  (Os0 dead after combine)
  u16* y2  = vn;    // lin1 out (Os1 dead after combine)
  u16* y3  = Qb;    // gelu out (Q dead after flash)

  conv_w_kernel<<<1024, 256, 0, stream>>>(q1w, k1w, v1w, pw, l1w, l2w, wq, wk, wv, wp2, wl1, wl2);
  ln_rows<<<MM, 256, 0, stream>>>(x, n1g, n1b, hbuf);
  qkv_pre<<<MM, 256, 0, stream>>>(hbuf, mask, qconv, kconv, vconv,
                                  qg, qbe, kg, kbe, vg, vbe, qn, kn, vn);
  gemm_qkv<<<dim3(64, 8, 3), 256, 0, stream>>>(qn, kn, vn, wq, wk, wv, q1b, k1b, v1b, Qb, Kb, Vtb);
  flash_attn<<<1024, 256, 0, stream>>>(Qb, Kb, Vtb, mask, Os0, Os1, Os2, Os3, stats);
  attn_combine<<<MM, 256, 0, stream>>>(Os0, Os1, Os2, Os3, stats, AO);
  gemm_bt<1><<<dim3(64, 8), 256, 0, stream>>>(AO, wp2, pb, x2b, x, mask);
  ln_rows_b2b<<<MM, 256, 0, stream>>>(x2b, n2g, n2b, y1);
  gemm_bt<0><<<dim3(64, 8), 256, 0, stream>>>(y1, wl1, l1b, y2, nullptr, nullptr);
  tc_gelu<<<MM, 256, 0, stream>>>(y2, tcw, tcb, y3);
  gemm_bt<2><<<dim3(64, 8), 256, 0, stream>>>(y3, wl2, l2b, (float*)d_out, x2b, nullptr);
}

// Round 16
// 332.911 us; speedup vs baseline: 3.2106x; 3.2106x over previous
//
#include <hip/hip_runtime.h>

#define BB 4
#define TT 2048
#define CC 1024
#define HH 4
#define DD 256
#define MM (BB*TT)

#define EPSV 1e-5f
#define NEGBIG (-1e30f)
#define SCALEV 0.0625f   // 1/sqrt(256)

typedef unsigned short u16;
typedef unsigned int   u32;
typedef __bf16 bf16x8 __attribute__((ext_vector_type(8)));
typedef float  f32x4  __attribute__((ext_vector_type(4)));
typedef float  f32x16 __attribute__((ext_vector_type(16)));

typedef u32 __attribute__((address_space(1))) gu32;
typedef u32 __attribute__((address_space(3))) lu32;

__device__ __forceinline__ u16 f2bf(float f){
  u32 u = __builtin_bit_cast(u32, f);
  u32 r = (u + 0x7fffu + ((u >> 16) & 1u)) >> 16;
  return (u16)r;
}
__device__ __forceinline__ float bf2f(u16 h){
  u32 u = ((u32)h) << 16;
  return __builtin_bit_cast(float, u);
}
__device__ __forceinline__ void gload_lds16(const u16* g, u16* l){
  __builtin_amdgcn_global_load_lds((const gu32*)g, (lu32*)l, 16, 0, 0);
}
__device__ __forceinline__ u32 cvtpk_bf16(float lo, float hi){
  u32 r;
  asm("v_cvt_pk_bf16_f32 %0, %1, %2" : "=v"(r) : "v"(lo), "v"(hi));
  return r;
}

// ---------------- weight f32 -> bf16 ----------------
__global__ __launch_bounds__(256) void conv_w_kernel(
    const float* __restrict__ w0, const float* __restrict__ w1, const float* __restrict__ w2,
    const float* __restrict__ w3, const float* __restrict__ w4, const float* __restrict__ w5,
    u16* __restrict__ o0, u16* __restrict__ o1, u16* __restrict__ o2,
    u16* __restrict__ o3, u16* __restrict__ o4, u16* __restrict__ o5){
  const int i = (blockIdx.x * 256 + threadIdx.x) * 4;
  const float* wsrc[6] = {w0,w1,w2,w3,w4,w5};
  u16* odst[6] = {o0,o1,o2,o3,o4,o5};
#pragma unroll
  for (int k = 0; k < 6; ++k){
    float4 v = *(const float4*)(wsrc[k] + i);
    ushort4 p; p.x=f2bf(v.x); p.y=f2bf(v.y); p.z=f2bf(v.z); p.w=f2bf(v.w);
    *(ushort4*)(odst[k] + i) = p;
  }
}

// ---------------- channel LayerNorm over C per (b,t) row (f32 in, bf16 out) ----------------
__global__ __launch_bounds__(256) void ln_rows(const float* __restrict__ x,
    const float* __restrict__ g, const float* __restrict__ be, u16* __restrict__ out){
  const int row = blockIdx.x, tid = threadIdx.x;
  const float4 v = ((const float4*)(x + (size_t)row * CC))[tid];
  float s  = v.x + v.y + v.z + v.w;
  float ss = v.x*v.x + v.y*v.y + v.z*v.z + v.w*v.w;
  __shared__ float sb[8];
#pragma unroll
  for (int o = 1; o < 64; o <<= 1){ s += __shfl_xor(s, o); ss += __shfl_xor(ss, o); }
  const int wid = tid >> 6, lane = tid & 63;
  if (lane == 0){ sb[wid] = s; sb[4 + wid] = ss; }
  __syncthreads();
  s  = sb[0] + sb[1] + sb[2] + sb[3];
  ss = sb[4] + sb[5] + sb[6] + sb[7];
  const float mu = s * (1.0f / CC);
  const float rstd = rsqrtf(ss * (1.0f / CC) - mu * mu + EPSV);
  const float4 gg = ((const float4*)g)[tid];
  const float4 bb = ((const float4*)be)[tid];
  ushort4 p;
  p.x = f2bf((v.x - mu) * rstd * gg.x + bb.x);
  p.y = f2bf((v.y - mu) * rstd * gg.y + bb.y);
  p.z = f2bf((v.z - mu) * rstd * gg.z + bb.z);
  p.w = f2bf((v.w - mu) * rstd * gg.w + bb.w);
  *(ushort4*)(out + (size_t)row * CC + tid * 4) = p;
}

// ---------------- channel LayerNorm, bf16 in -> bf16 out ----------------
__global__ __launch_bounds__(256) void ln_rows_b2b(const u16* __restrict__ x,
    const float* __restrict__ g, const float* __restrict__ be, u16* __restrict__ out){
  const int row = blockIdx.x, tid = threadIdx.x;
  const ushort4 u = ((const ushort4*)(x + (size_t)row * CC))[tid];
  const float v0 = bf2f(u.x), v1 = bf2f(u.y), v2 = bf2f(u.z), v3 = bf2f(u.w);
  float s  = v0 + v1 + v2 + v3;
  float ss = v0*v0 + v1*v1 + v2*v2 + v3*v3;
  __shared__ float sb[8];
#pragma unroll
  for (int o = 1; o < 64; o <<= 1){ s += __shfl_xor(s, o); ss += __shfl_xor(ss, o); }
  const int wid = tid >> 6, lane = tid & 63;
  if (lane == 0){ sb[wid] = s; sb[4 + wid] = ss; }
  __syncthreads();
  s  = sb[0] + sb[1] + sb[2] + sb[3];
  ss = sb[4] + sb[5] + sb[6] + sb[7];
  const float mu = s * (1.0f / CC);
  const float rstd = rsqrtf(ss * (1.0f / CC) - mu * mu + EPSV);
  const float4 gg = ((const float4*)g)[tid];
  const float4 bb = ((const float4*)be)[tid];
  ushort4 p;
  p.x = f2bf((v0 - mu) * rstd * gg.x + bb.x);
  p.y = f2bf((v1 - mu) * rstd * gg.y + bb.y);
  p.z = f2bf((v2 - mu) * rstd * gg.z + bb.z);
  p.w = f2bf((v3 - mu) * rstd * gg.w + bb.w);
  *(ushort4*)(out + (size_t)row * CC + tid * 4) = p;
}

// ------------ fused q/k/v: dwconv3 (pad1) * mask -> LN -> bf16 (bf16 input h) ------------
__global__ __launch_bounds__(256) void qkv_pre(const u16* __restrict__ h,
    const int* __restrict__ mask,
    const float* __restrict__ qw, const float* __restrict__ kw, const float* __restrict__ vw,
    const float* __restrict__ qg, const float* __restrict__ qb2,
    const float* __restrict__ kg, const float* __restrict__ kb2,
    const float* __restrict__ vg, const float* __restrict__ vb2,
    u16* __restrict__ qn, u16* __restrict__ kn, u16* __restrict__ vn){
  const int row = blockIdx.x, tid = threadIdx.x;
  const int t = row & (TT - 1);
  const float mf = mask[row] ? 1.f : 0.f;
  ushort4 z4; z4.x = z4.y = z4.z = z4.w = 0;
  const ushort4 x0 = ((const ushort4*)(h + (size_t)row * CC))[tid];
  const ushort4 xm = (t > 0)      ? ((const ushort4*)(h + (size_t)(row - 1) * CC))[tid] : z4;
  const ushort4 xp = (t < TT - 1) ? ((const ushort4*)(h + (size_t)(row + 1) * CC))[tid] : z4;
  const int c = tid * 4;
  const float am[4] = {bf2f(xm.x), bf2f(xm.y), bf2f(xm.z), bf2f(xm.w)};
  const float a0[4] = {bf2f(x0.x), bf2f(x0.y), bf2f(x0.z), bf2f(x0.w)};
  const float ap[4] = {bf2f(xp.x), bf2f(xp.y), bf2f(xp.z), bf2f(xp.w)};
  float yq[4], yk[4], yv[4];
  float sq=0.f, ssq=0.f, sk=0.f, ssk=0.f, sv=0.f, ssv=0.f;
#pragma unroll
  for (int i = 0; i < 4; ++i){
    const float* qwp = qw + (c + i) * 3;
    const float* kwp = kw + (c + i) * 3;
    const float* vwp = vw + (c + i) * 3;
    const float q_ = (am[i]*qwp[0] + a0[i]*qwp[1] + ap[i]*qwp[2]) * mf;
    const float k_ = (am[i]*kwp[0] + a0[i]*kwp[1] + ap[i]*kwp[2]) * mf;
    const float v_ = (am[i]*vwp[0] + a0[i]*vwp[1] + ap[i]*vwp[2]) * mf;
    yq[i]=q_; yk[i]=k_; yv[i]=v_;
    sq+=q_; ssq+=q_*q_; sk+=k_; ssk+=k_*k_; sv+=v_; ssv+=v_*v_;
  }
  __shared__ float sb[24];
#pragma unroll
  for (int o = 1; o < 64; o <<= 1){
    sq += __shfl_xor(sq, o); ssq += __shfl_xor(ssq, o);
    sk += __shfl_xor(sk, o); ssk += __shfl_xor(ssk, o);
    sv += __shfl_xor(sv, o); ssv += __shfl_xor(ssv, o);
  }
  const int wid = tid >> 6, lane = tid & 63;
  if (lane == 0){
    sb[wid]=sq; sb[4+wid]=ssq; sb[8+wid]=sk; sb[12+wid]=ssk; sb[16+wid]=sv; sb[20+wid]=ssv;
  }
  __syncthreads();
  sq  = sb[0]+sb[1]+sb[2]+sb[3];    ssq = sb[4]+sb[5]+sb[6]+sb[7];
  sk  = sb[8]+sb[9]+sb[10]+sb[11];  ssk = sb[12]+sb[13]+sb[14]+sb[15];
  sv  = sb[16]+sb[17]+sb[18]+sb[19];ssv = sb[20]+sb[21]+sb[22]+sb[23];
  {
    const float mu = sq * (1.f/CC), rstd = rsqrtf(ssq*(1.f/CC) - mu*mu + EPSV);
    ushort4 p;
    p.x = f2bf((yq[0]-mu)*rstd*qg[c+0] + qb2[c+0]);
    p.y = f2bf((yq[1]-mu)*rstd*qg[c+1] + qb2[c+1]);
    p.z = f2bf((yq[2]-mu)*rstd*qg[c+2] + qb2[c+2]);
    p.w = f2bf((yq[3]-mu)*rstd*qg[c+3] + qb2[c+3]);
    *(ushort4*)(qn + (size_t)row * CC + c) = p;
  }
  {
    const float mu = sk * (1.f/CC), rstd = rsqrtf(ssk*(1.f/CC) - mu*mu + EPSV);
    ushort4 p;
    p.x = f2bf((yk[0]-mu)*rstd*kg[c+0] + kb2[c+0]);
    p.y = f2bf((yk[1]-mu)*rstd*kg[c+1] + kb2[c+1]);
    p.z = f2bf((yk[2]-mu)*rstd*kg[c+2] + kb2[c+2]);
    p.w = f2bf((yk[3]-mu)*rstd*kg[c+3] + kb2[c+3]);
    *(ushort4*)(kn + (size_t)row * CC + c) = p;
  }
  {
    const float mu = sv * (1.f/CC), rstd = rsqrtf(ssv*(1.f/CC) - mu*mu + EPSV);
    ushort4 p;
    p.x = f2bf((yv[0]-mu)*rstd*vg[c+0] + vb2[c+0]);
    p.y = f2bf((yv[1]-mu)*rstd*vg[c+1] + vb2[c+1]);
    p.z = f2bf((yv[2]-mu)*rstd*vg[c+2] + vb2[c+2]);
    p.w = f2bf((yv[3]-mu)*rstd*vg[c+3] + vb2[c+3]);
    *(ushort4*)(vn + (size_t)row * CC + c) = p;
  }
}

// ---------------- shared GEMM main loop v2: BK=64, double-buffered prefetch (T3 2-phase) ----------------
__device__ __forceinline__ void gemm_core(const u16* __restrict__ A, const u16* __restrict__ Bw,
    u16* As, u16* Bs, f32x4 acc[4][4], int bm, int bn, int tid){
  const int lane = tid & 63, wid = tid >> 6;
  const int wr = wid >> 1, wc = wid & 1;
  const int la = lane & 15, lg = lane >> 4;
  const int srow = tid >> 3;
  const int schunk = (tid & 7) ^ (srow & 7);
  const u16* gA = A  + (size_t)(bm * 128 + srow) * CC + schunk * 8;
  const u16* gB = Bw + (size_t)(bn * 128 + srow) * CC + schunk * 8;
  const int swz = (la & 7) << 4;
  auto stage = [&](int KT, int BUF){
    u16* dA = As + BUF * 8192 + tid * 8;
    u16* dB = Bs + BUF * 8192 + tid * 8;
#pragma unroll
    for (int i = 0; i < 4; ++i){
      gload_lds16(gA + (size_t)(i * 32) * CC + KT * 64, dA + i * 2048);
      gload_lds16(gB + (size_t)(i * 32) * CC + KT * 64, dB + i * 2048);
    }
  };
  stage(0, 0);
  __syncthreads();
  for (int kt = 0; kt < CC / 64; ++kt){
    const int cur = kt & 1;
    if (kt + 1 < CC / 64) stage(kt + 1, cur ^ 1);   // in flight across the compute phase
    const char* AsB = (const char*)(As + cur * 8192);
    const char* BsB = (const char*)(Bs + cur * 8192);
#pragma unroll
    for (int kk = 0; kk < 2; ++kk){
      bf16x8 af[4], bf[4];
      const int co = (kk * 64 + lg * 16) ^ swz;
#pragma unroll
      for (int mi = 0; mi < 4; ++mi)
        af[mi] = *(const bf16x8*)(AsB + (wr * 64 + mi * 16 + la) * 128 + co);
#pragma unroll
      for (int ni = 0; ni < 4; ++ni)
        bf[ni] = *(const bf16x8*)(BsB + (wc * 64 + ni * 16 + la) * 128 + co);
#pragma unroll
      for (int mi = 0; mi < 4; ++mi)
#pragma unroll
        for (int ni = 0; ni < 4; ++ni)
          acc[mi][ni] = __builtin_amdgcn_mfma_f32_16x16x32_bf16(af[mi], bf[ni], acc[mi][ni], 0, 0, 0);
    }
    __syncthreads();   // readers of buf[cur] done; stage into buf[cur^1] drained (vmcnt 0)
  }
}

// MODE 0: out bf16 (M,C).
// MODE 1: out bf16 = (acc+bias)*mask[m] + resid_f32[m,n]
// MODE 2: out f32  = acc + bias + resid_bf16[m,n]
template<int MODE>
__global__ __launch_bounds__(256, 2) void gemm_bt(
    const u16* __restrict__ A, const u16* __restrict__ Bw,
    const float* __restrict__ bias, void* __restrict__ out,
    const void* __restrict__ resid, const int* __restrict__ mask){
  __shared__ __align__(16) u16 As[2 * 8192];
  __shared__ __align__(16) u16 Bs[2 * 8192];
  const int tid = threadIdx.x, lane = tid & 63, wid = tid >> 6;
  const int wr = wid >> 1, wc = wid & 1;
  const int bm = blockIdx.x, bn = blockIdx.y;
  f32x4 acc[4][4];
#pragma unroll
  for (int i = 0; i < 4; ++i)
#pragma unroll
    for (int j = 0; j < 4; ++j) acc[i][j] = (f32x4){0.f, 0.f, 0.f, 0.f};
  gemm_core(A, Bw, As, Bs, acc, bm, bn, tid);
  const int la = lane & 15, lg = lane >> 4;
#pragma unroll
  for (int mi = 0; mi < 4; ++mi){
    const int mb = bm * 128 + wr * 64 + mi * 16 + lg * 4;
#pragma unroll
    for (int ni = 0; ni < 4; ++ni){
      const int n = bn * 128 + wc * 64 + ni * 16 + la;
      const float bz = bias[n];
      if (MODE == 0){
        u16* o = (u16*)out;
#pragma unroll
        for (int j = 0; j < 4; ++j) o[(size_t)(mb + j) * CC + n] = f2bf(acc[mi][ni][j] + bz);
      } else if (MODE == 1){
        u16* o = (u16*)out;
        const float* r = (const float*)resid;
#pragma unroll
        for (int j = 0; j < 4; ++j){
          const int m = mb + j;
          const float mf = mask[m] ? 1.f : 0.f;
          o[(size_t)m * CC + n] = f2bf((acc[mi][ni][j] + bz) * mf + r[(size_t)m * CC + n]);
        }
      } else {
        float* o = (float*)out;
        const u16* r = (const u16*)resid;
#pragma unroll
        for (int j = 0; j < 4; ++j){
          const int m = mb + j;
          o[(size_t)m * CC + n] = acc[mi][ni][j] + bz + bf2f(r[(size_t)m * CC + n]);
        }
      }
    }
  }
}

// fused q/k/v projection: z selects input/weight/bias/output; z==2 writes V transposed (B,H,D,T)
__global__ __launch_bounds__(256, 2) void gemm_qkv(
    const u16* __restrict__ qn, const u16* __restrict__ kn, const u16* __restrict__ vn,
    const u16* __restrict__ wq, const u16* __restrict__ wk, const u16* __restrict__ wv,
    const float* __restrict__ qb, const float* __restrict__ kb, const float* __restrict__ vb,
    u16* __restrict__ Qb, u16* __restrict__ Kb, u16* __restrict__ Vtb){
  __shared__ __align__(16) u16 As[2 * 8192];
  __shared__ __align__(16) u16 Bs[2 * 8192];
  const int z = blockIdx.z;
  const u16* A  = (z == 0) ? qn : (z == 1) ? kn : vn;
  const u16* Bw = (z == 0) ? wq : (z == 1) ? wk : wv;
  const float* bias = (z == 0) ? qb : (z == 1) ? kb : vb;
  const int tid = threadIdx.x, lane = tid & 63, wid = tid >> 6;
  const int wr = wid >> 1, wc = wid & 1;
  const int bm = blockIdx.x, bn = blockIdx.y;
  f32x4 acc[4][4];
#pragma unroll
  for (int i = 0; i < 4; ++i)
#pragma unroll
    for (int j = 0; j < 4; ++j) acc[i][j] = (f32x4){0.f, 0.f, 0.f, 0.f};
  gemm_core(A, Bw, As, Bs, acc, bm, bn, tid);
  const int la = lane & 15, lg = lane >> 4;
#pragma unroll
  for (int mi = 0; mi < 4; ++mi){
    const int mb = bm * 128 + wr * 64 + mi * 16 + lg * 4;
#pragma unroll
    for (int ni = 0; ni < 4; ++ni){
      const int n = bn * 128 + wc * 64 + ni * 16 + la;
      const float bz = bias[n];
      if (z < 2){
        u16* o = z ? Kb : Qb;
#pragma unroll
        for (int j = 0; j < 4; ++j) o[(size_t)(mb + j) * CC + n] = f2bf(acc[mi][ni][j] + bz);
      } else {
        const int bq = mb >> 11, tq = mb & (TT - 1);
        const int hq = n >> 8, dq = n & 255;
        ushort4 p;
        p.x = f2bf(acc[mi][ni][0] + bz); p.y = f2bf(acc[mi][ni][1] + bz);
        p.z = f2bf(acc[mi][ni][2] + bz); p.w = f2bf(acc[mi][ni][3] + bz);
        *(ushort4*)&Vtb[(size_t)((bq * HH + hq) * DD + dq) * TT + tq] = p;
      }
    }
  }
}

// ---------------- flash attention v12: kv-split=4, grid 1024, launch_bounds(256,2) ----------------
// Wave = 32 q; block = 4 waves = 128 q; KVB=32; LDS 32KB; unnormalized partials + stats.
// 128 VGPR/wave -> HW packs 4 blocks/CU (16 waves x 128 = 512/SIMD exactly).
// XCD x: h2 = x>>1; sp in {x&1, (x&1)+2}; all batches -> per-XCD work balanced.
// D layout (m74/m101): col=lane&31 (=q), row=(reg&3)+8*(reg>>2)+4*(lane>>5) (=k or d).
__global__ __launch_bounds__(256, 2) void flash_attn(
    const u16* __restrict__ Q, const u16* __restrict__ Kg,
    const u16* __restrict__ Vt, const int* __restrict__ mask,
    u16* __restrict__ Os0, u16* __restrict__ Os1,
    u16* __restrict__ Os2, u16* __restrict__ Os3, float2* __restrict__ stats){
  __shared__ __align__(16) u16 Ks[32 * 256];   // 16KB: row k 512B, chunk ^= (r&7)
  __shared__ __align__(16) u16 Vs[256 * 32];   // 16KB: row d 64B, chunk ^= ((d>>1)&3)
  const int Dn = blockIdx.x;
  const int xcd = Dn & 7, rest = Dn >> 3;      // rest 0..127
  const int h2 = xcd >> 1;
  const int sp = (xcd & 1) | ((rest >> 6) << 1);   // 0..3 kv-split quarter
  const int b = (rest >> 4) & 3, qt = rest & 15;
  const int bh = b * HH + h2;
  const int tid = threadIdx.x, lane = tid & 63, wid = tid >> 6;
  const int l31 = lane & 31, hi = lane >> 5;

  // ---- sequence length via two ballot rounds (prefix mask, len in [1024,2048]) ----
  const int* mrow = mask + b * TT;
  int len = 1024;
  {
    unsigned long long bal = __ballot(mrow[1024 + lane * 16] != 0);
    int ones = __popcll(bal);
    if (ones > 0){
      int lo = 1024 + (ones - 1) * 16;
      unsigned long long bal2 = __ballot(mrow[lo + (lane & 15)] != 0);
      len = lo + __popcll(bal2 & 0xFFFFull);
    }
  }
  const int nkt = (len + 31) >> 5;
  const int t0 = (sp * nkt) >> 2, t1 = ((sp + 1) * nkt) >> 2;

  // ---- Q fragments: lane holds q = q0 + l31, d = kd*16 + hi*8 .. +8 ----
  const int q0 = qt * 128 + wid * 32;
  bf16x8 qf[16];
  const u16* qrow = Q + (size_t)(b * TT + q0 + l31) * CC + h2 * DD + hi * 8;
#pragma unroll
  for (int kd = 0; kd < 16; ++kd) qf[kd] = *(const bf16x8*)(qrow + kd * 16);

  f32x16 acc[8];
#pragma unroll
  for (int i = 0; i < 8; ++i)
#pragma unroll
    for (int r = 0; r < 16; ++r) acc[i][r] = 0.f;
  float mrun = NEGBIG, lrun = 0.f;

  // ---- staging (pre-swizzled global source, linear LDS dest) ----
  const int krow = tid >> 5;
  const int kc = (tid & 31) ^ (krow & 7);
  const u16* ksrc = Kg + (size_t)(b * TT + krow) * CC + h2 * DD + kc * 8;
  const int vc = (tid & 3) ^ ((tid >> 3) & 3);
  const u16* vsrcb = Vt + (size_t)(bh * DD + (tid >> 2)) * TT + vc * 8;

#define STAGE_K(KT) { _Pragma("unroll") \
  for (int i = 0; i < 4; ++i) \
    gload_lds16(ksrc + (size_t)((KT) * 32 + i * 8) * CC, Ks + i * 2048 + tid * 8); }
#define STAGE_V(KT) { _Pragma("unroll") \
  for (int i = 0; i < 4; ++i) \
    gload_lds16(vsrcb + (size_t)(i * 64) * TT + (KT) * 32, Vs + i * 2048 + tid * 8); }

  STAGE_K(t0); STAGE_V(t0);
  __syncthreads();

  const char* KsB = (const char*)Ks;
  const char* VsB = (const char*)Vs;
  const int swk = (l31 & 7) << 4;          // K read byte-XOR (row = l31)
  const int swv = ((l31 >> 1) & 3) << 4;   // V read byte-XOR (row = dt*32+l31)
  const float sc2 = SCALEV * 1.44269504f;  // softmax in exp2 domain

  for (int kt = t0; kt < t1; ++kt){
    // ---- QK^T: S^T(32k x 32q) = K_tile * Q^T over 16 d-slices ----
    f32x16 s;
#pragma unroll
    for (int r = 0; r < 16; ++r) s[r] = 0.f;
#pragma unroll
    for (int kd = 0; kd < 16; ++kd){
      bf16x8 kf = *(const bf16x8*)(KsB + l31 * 512 + ((kd * 32 + hi * 16) ^ swk));
      s = __builtin_amdgcn_mfma_f32_32x32x16_bf16(kf, qf[kd], s, 0, 0, 0);
    }
    // scale + tail mask: lane reg r -> k = kt*32 + (r&3) + 8*(r>>2) + 4*hi
    if (kt * 32 + 32 <= len){
      s *= sc2;
    } else {
#pragma unroll
      for (int r = 0; r < 16; ++r){
        const int k = kt * 32 + (r & 3) + 8 * (r >> 2) + 4 * hi;
        s[r] = (k < len) ? s[r] * sc2 : NEGBIG;
      }
    }
    // ---- online softmax: q = l31 lane-local; k-halves split across lane^32 ----
    float tm = s[0];
#pragma unroll
    for (int r = 1; r < 16; ++r) tm = fmaxf(tm, s[r]);
    tm = fmaxf(tm, __shfl_xor(tm, 32));
    if (!__all(tm <= mrun + 12.0f)){   // defer-max
      const float mn = fmaxf(mrun, tm);
      const float al = __builtin_exp2f(mrun - mn);
      mrun = mn; lrun *= al;
#pragma unroll
      for (int i = 0; i < 8; ++i) acc[i] *= al;
    }
    float p[16];
    float ts = 0.f;
#pragma unroll
    for (int r = 0; r < 16; ++r){ p[r] = __builtin_exp2f(s[r] - mrun); ts += p[r]; }
    ts += __shfl_xor(ts, 32);
    lrun += ts;
    // ---- pack P to bf16 pairs and build PV B-frags via permlane32_swap ----
    u32 w0 = cvtpk_bf16(p[0],  p[1]),  w1 = cvtpk_bf16(p[2],  p[3]);
    u32 w2 = cvtpk_bf16(p[4],  p[5]),  w3 = cvtpk_bf16(p[6],  p[7]);
    u32 w4 = cvtpk_bf16(p[8],  p[9]),  w5 = cvtpk_bf16(p[10], p[11]);
    u32 w6 = cvtpk_bf16(p[12], p[13]), w7 = cvtpk_bf16(p[14], p[15]);
    asm("v_permlane32_swap_b32 %0, %1" : "+v"(w0), "+v"(w2));
    asm("v_permlane32_swap_b32 %0, %1" : "+v"(w1), "+v"(w3));
    asm("v_permlane32_swap_b32 %0, %1" : "+v"(w4), "+v"(w6));
    asm("v_permlane32_swap_b32 %0, %1" : "+v"(w5), "+v"(w7));
    u32 pb0u[4] = {w0, w1, w2, w3};   // k = hi*8 + 0..7
    u32 pb1u[4] = {w4, w5, w6, w7};   // k = 16 + hi*8 + 0..7
    bf16x8 pb0 = __builtin_bit_cast(bf16x8, *(uint4*)pb0u);
    bf16x8 pb1 = __builtin_bit_cast(bf16x8, *(uint4*)pb1u);
    __syncthreads();   // b1: Ks readers done; V(kt) stage drained
    if (kt + 1 < t1) STAGE_K(kt + 1);   // hides under PV, drained at b2
    // ---- PV: O^T(d x q) += V^T_tile * P^T ----
#pragma unroll
    for (int dt = 0; dt < 8; ++dt){
      const char* vr = VsB + (dt * 32 + l31) * 64;
      bf16x8 vf0 = *(const bf16x8*)(vr + ((hi * 16) ^ swv));
      acc[dt] = __builtin_amdgcn_mfma_f32_32x32x16_bf16(vf0, pb0, acc[dt], 0, 0, 0);
      bf16x8 vf1 = *(const bf16x8*)(vr + ((32 + hi * 16) ^ swv));
      acc[dt] = __builtin_amdgcn_mfma_f32_32x32x16_bf16(vf1, pb1, acc[dt], 0, 0, 0);
    }
    __syncthreads();   // b2: Vs readers done; K(kt+1) stage drained
    if (kt + 1 < t1) STAGE_V(kt + 1);   // drained at next b1
  }
  // ---- epilogue: unnormalized partial O + (m,l) stats ----
  u16* Os = (sp == 0) ? Os0 : (sp == 1) ? Os1 : (sp == 2) ? Os2 : Os3;
  u16* orow = Os + (size_t)(b * TT + q0 + l31) * CC + h2 * DD + hi * 4;
#pragma unroll
  for (int dt = 0; dt < 8; ++dt)
#pragma unroll
    for (int rg = 0; rg < 4; ++rg){
      ushort4 pk;
      pk.x = f2bf(acc[dt][rg * 4 + 0]); pk.y = f2bf(acc[dt][rg * 4 + 1]);
      pk.z = f2bf(acc[dt][rg * 4 + 2]); pk.w = f2bf(acc[dt][rg * 4 + 3]);
      *(ushort4*)(orow + dt * 32 + rg * 8) = pk;
    }
  if (lane < 32)
    stats[(size_t)((sp * 16 + bh) << 11) + q0 + l31] = make_float2(mrun, lrun);
#undef STAGE_K
#undef STAGE_V
}

// ---------------- combine the four kv-split partials ----------------
__global__ __launch_bounds__(256) void attn_combine(
    const u16* __restrict__ Os0, const u16* __restrict__ Os1,
    const u16* __restrict__ Os2, const u16* __restrict__ Os3,
    const float2* __restrict__ stats, u16* __restrict__ AO){
  const int row = blockIdx.x, tid = threadIdx.x;
  const int b = row >> 11, q = row & (TT - 1);
  const int h2 = tid >> 6;
  const int bh = b * HH + h2;
  const float2 s0 = stats[(size_t)(( 0 + bh) << 11) + q];
  const float2 s1 = stats[(size_t)((16 + bh) << 11) + q];
  const float2 s2 = stats[(size_t)((32 + bh) << 11) + q];
  const float2 s3 = stats[(size_t)((48 + bh) << 11) + q];
  const float m = fmaxf(fmaxf(s0.x, s1.x), fmaxf(s2.x, s3.x));
  const float e0 = __builtin_exp2f(s0.x - m), e1 = __builtin_exp2f(s1.x - m);
  const float e2 = __builtin_exp2f(s2.x - m), e3 = __builtin_exp2f(s3.x - m);
  const float l = s0.y * e0 + s1.y * e1 + s2.y * e2 + s3.y * e3;
  const float f0 = e0 / l, f1 = e1 / l, f2 = e2 / l, f3 = e3 / l;
  const size_t off = (size_t)row * CC + tid * 4;
  const ushort4 a0 = *(const ushort4*)(Os0 + off);
  const ushort4 a1 = *(const ushort4*)(Os1 + off);
  const ushort4 a2 = *(const ushort4*)(Os2 + off);
  const ushort4 a3 = *(const ushort4*)(Os3 + off);
  ushort4 o;
  o.x = f2bf(bf2f(a0.x) * f0 + bf2f(a1.x) * f1 + bf2f(a2.x) * f2 + bf2f(a3.x) * f3);
  o.y = f2bf(bf2f(a0.y) * f0 + bf2f(a1.y) * f1 + bf2f(a2.y) * f2 + bf2f(a3.y) * f3);
  o.z = f2bf(bf2f(a0.z) * f0 + bf2f(a1.z) * f1 + bf2f(a2.z) * f2 + bf2f(a3.z) * f3);
  o.w = f2bf(bf2f(a0.w) * f0 + bf2f(a1.w) * f1 + bf2f(a2.w) * f2 + bf2f(a3.w) * f3);
  *(ushort4*)(AO + off) = o;
}

// ---------------- dwconv(tc) + bias + exact GELU ----------------
__global__ __launch_bounds__(256) void tc_gelu(const u16* __restrict__ y2,
    const float* __restrict__ w, const float* __restrict__ bias, u16* __restrict__ y3){
  const int row = blockIdx.x, tid = threadIdx.x;
  const int t = row & (TT - 1);
  const int c = tid * 4;
  ushort4 z4; z4.x = z4.y = z4.z = z4.w = 0;
  const ushort4 u0 = *(const ushort4*)(y2 + (size_t)row * CC + c);
  const ushort4 um = (t > 0)      ? *(const ushort4*)(y2 + (size_t)(row - 1) * CC + c) : z4;
  const ushort4 up = (t < TT - 1) ? *(const ushort4*)(y2 + (size_t)(row + 1) * CC + c) : z4;
  const float am[4] = {bf2f(um.x), bf2f(um.y), bf2f(um.z), bf2f(um.w)};
  const float a0[4] = {bf2f(u0.x), bf2f(u0.y), bf2f(u0.z), bf2f(u0.w)};
  const float ap[4] = {bf2f(up.x), bf2f(up.y), bf2f(up.z), bf2f(up.w)};
  u16 pv[4];
#pragma unroll
  for (int i = 0; i < 4; ++i){
    const float* wp = w + (c + i) * 3;
    const float yv = am[i] * wp[0] + a0[i] * wp[1] + ap[i] * wp[2] + bias[c + i];
    const float ge = 0.5f * yv * (1.f + erff(yv * 0.7071067811865475f));
    pv[i] = f2bf(ge);
  }
  ushort4 p; p.x = pv[0]; p.y = pv[1]; p.z = pv[2]; p.w = pv[3];
  *(ushort4*)(y3 + (size_t)row * CC + c) = p;
}

extern "C" void kernel_launch(void* const* d_in, const int* in_sizes, int n_in,
                              void* d_out, int out_size, void* d_ws, size_t ws_size,
                              hipStream_t stream){
  const float* x     = (const float*)d_in[0];
  const int*   mask  = (const int*)d_in[1];
  const float* n1g   = (const float*)d_in[2];
  const float* n1b   = (const float*)d_in[3];
  const float* qconv = (const float*)d_in[4];
  const float* kconv = (const float*)d_in[5];
  const float* vconv = (const float*)d_in[6];
  const float* qg    = (const float*)d_in[7];
  const float* qbe   = (const float*)d_in[8];
  const float* kg    = (const float*)d_in[9];
  const float* kbe   = (const float*)d_in[10];
  const float* vg    = (const float*)d_in[11];
  const float* vbe   = (const float*)d_in[12];
  const float* q1w   = (const float*)d_in[13];
  const float* q1b   = (const float*)d_in[14];
  const float* k1w   = (const float*)d_in[15];
  const float* k1b   = (const float*)d_in[16];
  const float* v1w   = (const float*)d_in[17];
  const float* v1b   = (const float*)d_in[18];
  const float* pw    = (const float*)d_in[19];
  const float* pb    = (const float*)d_in[20];
  const float* n2g   = (const float*)d_in[21];
  const float* n2b   = (const float*)d_in[22];
  const float* l1w   = (const float*)d_in[23];
  const float* l1b   = (const float*)d_in[24];
  const float* tcw   = (const float*)d_in[25];
  const float* tcb   = (const float*)d_in[26];
  const float* l2w   = (const float*)d_in[27];
  const float* l2b   = (const float*)d_in[28];
  (void)in_sizes; (void)n_in; (void)out_size; (void)ws_size;

  char* ws = (char*)d_ws;
  const size_t MB = (size_t)1 << 20;
  u16* wq  = (u16*)(ws + 0 * MB);
  u16* wk  = (u16*)(ws + 2 * MB);
  u16* wv  = (u16*)(ws + 4 * MB);
  u16* wp2 = (u16*)(ws + 6 * MB);
  u16* wl1 = (u16*)(ws + 8 * MB);
  u16* wl2 = (u16*)(ws + 10 * MB);
  u16* hbuf = (u16*)(ws + 12 * MB);   // 16 MB bf16 LN1 output; dead after qkv_pre
  u16* Os2  = (u16*)(ws + 12 * MB);   // kv-split partial 2 (aliases hbuf; written by flash)
  u16* x2b  = (u16*)(ws + 12 * MB);   // 16 MB bf16 residual; written by gemm_bt<1> AFTER combine
  u16* Os3  = (u16*)(ws + 28 * MB);   // kv-split partial 3
  u16* qn  = (u16*)(ws + 44 * MB);
  u16* kn  = (u16*)(ws + 60 * MB);
  u16* vn  = (u16*)(ws + 76 * MB);
  u16* Qb  = (u16*)(ws + 92 * MB);
  u16* Kb  = (u16*)(ws + 108 * MB);
  u16* Vtb = (u16*)(ws + 124 * MB);
  float2* stats = (float2*)(ws + 140 * MB);   // 1 MB
  u16* AO  = qn;    // attnout  (qn dead after qkv GEMM)
  u16* Os0 = kn;    // kv-split partial 0 (kn dead after qkv GEMM)
  u16* Os1 = vn;    // kv-split partial 1 (vn dead after qkv GEMM)
  u16* y1  = kn;    // LN2 out  (Os0 dead after combine)
  u16* y2  = vn;    // lin1 out (Os1 dead after combine)
  u16* y3  = Qb;    // gelu out (Q dead after flash)

  conv_w_kernel<<<1024, 256, 0, stream>>>(q1w, k1w, v1w, pw, l1w, l2w, wq, wk, wv, wp2, wl1, wl2);
  ln_rows<<<MM, 256, 0, stream>>>(x, n1g, n1b, hbuf);
  qkv_pre<<<MM, 256, 0, stream>>>(hbuf, mask, qconv, kconv, vconv,
                                  qg, qbe, kg, kbe, vg, vbe, qn, kn, vn);
  gemm_qkv<<<dim3(64, 8, 3), 256, 0, stream>>>(qn, kn, vn, wq, wk, wv, q1b, k1b, v1b, Qb, Kb, Vtb);
  flash_attn<<<1024, 256, 0, stream>>>(Qb, Kb, Vtb, mask, Os0, Os1, Os2, Os3, stats);
  attn_combine<<<MM, 256, 0, stream>>>(Os0, Os1, Os2, Os3, stats, AO);
  gemm_bt<1><<<dim3(64, 8), 256, 0, stream>>>(AO, wp2, pb, x2b, x, mask);
  ln_rows_b2b<<<MM, 256, 0, stream>>>(x2b, n2g, n2b, y1);
  gemm_bt<0><<<dim3(64, 8), 256, 0, stream>>>(y1, wl1, l1b, y2, nullptr, nullptr);
  tc_gelu<<<MM, 256, 0, stream>>>(y2, tcw, tcb, y3);
  gemm_bt<2><<<dim3(64, 8), 256, 0, stream>>>(y3, wl2, l2b, (float*)d_out, x2b, nullptr);
}

// Round 17
// 312.530 us; speedup vs baseline: 3.4199x; 1.0652x over previous
//
#include <hip/hip_runtime.h>

#define BB 4
#define TT 2048
#define CC 1024
#define HH 4
#define DD 256
#define MM (BB*TT)

#define EPSV 1e-5f
#define NEGBIG (-1e30f)
#define SCALEV 0.0625f   // 1/sqrt(256)

typedef unsigned short u16;
typedef unsigned int   u32;
typedef __bf16 bf16x8 __attribute__((ext_vector_type(8)));
typedef float  f32x4  __attribute__((ext_vector_type(4)));
typedef float  f32x16 __attribute__((ext_vector_type(16)));

typedef u32 __attribute__((address_space(1))) gu32;
typedef u32 __attribute__((address_space(3))) lu32;

__device__ __forceinline__ u16 f2bf(float f){
  u32 u = __builtin_bit_cast(u32, f);
  u32 r = (u + 0x7fffu + ((u >> 16) & 1u)) >> 16;
  return (u16)r;
}
__device__ __forceinline__ float bf2f(u16 h){
  u32 u = ((u32)h) << 16;
  return __builtin_bit_cast(float, u);
}
__device__ __forceinline__ void gload_lds16(const u16* g, u16* l){
  __builtin_amdgcn_global_load_lds((const gu32*)g, (lu32*)l, 16, 0, 0);
}
__device__ __forceinline__ u32 cvtpk_bf16(float lo, float hi){
  u32 r;
  asm("v_cvt_pk_bf16_f32 %0, %1, %2" : "=v"(r) : "v"(lo), "v"(hi));
  return r;
}

// ---------------- weight f32 -> bf16 ----------------
__global__ __launch_bounds__(256) void conv_w_kernel(
    const float* __restrict__ w0, const float* __restrict__ w1, const float* __restrict__ w2,
    const float* __restrict__ w3, const float* __restrict__ w4, const float* __restrict__ w5,
    u16* __restrict__ o0, u16* __restrict__ o1, u16* __restrict__ o2,
    u16* __restrict__ o3, u16* __restrict__ o4, u16* __restrict__ o5){
  const int i = (blockIdx.x * 256 + threadIdx.x) * 4;
  const float* wsrc[6] = {w0,w1,w2,w3,w4,w5};
  u16* odst[6] = {o0,o1,o2,o3,o4,o5};
#pragma unroll
  for (int k = 0; k < 6; ++k){
    float4 v = *(const float4*)(wsrc[k] + i);
    ushort4 p; p.x=f2bf(v.x); p.y=f2bf(v.y); p.z=f2bf(v.z); p.w=f2bf(v.w);
    *(ushort4*)(odst[k] + i) = p;
  }
}

// ---------------- channel LayerNorm over C per (b,t) row (f32 in, bf16 out) ----------------
__global__ __launch_bounds__(256) void ln_rows(const float* __restrict__ x,
    const float* __restrict__ g, const float* __restrict__ be, u16* __restrict__ out){
  const int row = blockIdx.x, tid = threadIdx.x;
  const float4 v = ((const float4*)(x + (size_t)row * CC))[tid];
  float s  = v.x + v.y + v.z + v.w;
  float ss = v.x*v.x + v.y*v.y + v.z*v.z + v.w*v.w;
  __shared__ float sb[8];
#pragma unroll
  for (int o = 1; o < 64; o <<= 1){ s += __shfl_xor(s, o); ss += __shfl_xor(ss, o); }
  const int wid = tid >> 6, lane = tid & 63;
  if (lane == 0){ sb[wid] = s; sb[4 + wid] = ss; }
  __syncthreads();
  s  = sb[0] + sb[1] + sb[2] + sb[3];
  ss = sb[4] + sb[5] + sb[6] + sb[7];
  const float mu = s * (1.0f / CC);
  const float rstd = rsqrtf(ss * (1.0f / CC) - mu * mu + EPSV);
  const float4 gg = ((const float4*)g)[tid];
  const float4 bb = ((const float4*)be)[tid];
  ushort4 p;
  p.x = f2bf((v.x - mu) * rstd * gg.x + bb.x);
  p.y = f2bf((v.y - mu) * rstd * gg.y + bb.y);
  p.z = f2bf((v.z - mu) * rstd * gg.z + bb.z);
  p.w = f2bf((v.w - mu) * rstd * gg.w + bb.w);
  *(ushort4*)(out + (size_t)row * CC + tid * 4) = p;
}

// ---------------- channel LayerNorm, bf16 in -> bf16 out ----------------
__global__ __launch_bounds__(256) void ln_rows_b2b(const u16* __restrict__ x,
    const float* __restrict__ g, const float* __restrict__ be, u16* __restrict__ out){
  const int row = blockIdx.x, tid = threadIdx.x;
  const ushort4 u = ((const ushort4*)(x + (size_t)row * CC))[tid];
  const float v0 = bf2f(u.x), v1 = bf2f(u.y), v2 = bf2f(u.z), v3 = bf2f(u.w);
  float s  = v0 + v1 + v2 + v3;
  float ss = v0*v0 + v1*v1 + v2*v2 + v3*v3;
  __shared__ float sb[8];
#pragma unroll
  for (int o = 1; o < 64; o <<= 1){ s += __shfl_xor(s, o); ss += __shfl_xor(ss, o); }
  const int wid = tid >> 6, lane = tid & 63;
  if (lane == 0){ sb[wid] = s; sb[4 + wid] = ss; }
  __syncthreads();
  s  = sb[0] + sb[1] + sb[2] + sb[3];
  ss = sb[4] + sb[5] + sb[6] + sb[7];
  const float mu = s * (1.0f / CC);
  const float rstd = rsqrtf(ss * (1.0f / CC) - mu * mu + EPSV);
  const float4 gg = ((const float4*)g)[tid];
  const float4 bb = ((const float4*)be)[tid];
  ushort4 p;
  p.x = f2bf((v0 - mu) * rstd * gg.x + bb.x);
  p.y = f2bf((v1 - mu) * rstd * gg.y + bb.y);
  p.z = f2bf((v2 - mu) * rstd * gg.z + bb.z);
  p.w = f2bf((v3 - mu) * rstd * gg.w + bb.w);
  *(ushort4*)(out + (size_t)row * CC + tid * 4) = p;
}

// ------------ fused q/k/v: dwconv3 (pad1) * mask -> LN -> bf16 (bf16 input h) ------------
__global__ __launch_bounds__(256) void qkv_pre(const u16* __restrict__ h,
    const int* __restrict__ mask,
    const float* __restrict__ qw, const float* __restrict__ kw, const float* __restrict__ vw,
    const float* __restrict__ qg, const float* __restrict__ qb2,
    const float* __restrict__ kg, const float* __restrict__ kb2,
    const float* __restrict__ vg, const float* __restrict__ vb2,
    u16* __restrict__ qn, u16* __restrict__ kn, u16* __restrict__ vn){
  const int row = blockIdx.x, tid = threadIdx.x;
  const int t = row & (TT - 1);
  const float mf = mask[row] ? 1.f : 0.f;
  ushort4 z4; z4.x = z4.y = z4.z = z4.w = 0;
  const ushort4 x0 = ((const ushort4*)(h + (size_t)row * CC))[tid];
  const ushort4 xm = (t > 0)      ? ((const ushort4*)(h + (size_t)(row - 1) * CC))[tid] : z4;
  const ushort4 xp = (t < TT - 1) ? ((const ushort4*)(h + (size_t)(row + 1) * CC))[tid] : z4;
  const int c = tid * 4;
  const float am[4] = {bf2f(xm.x), bf2f(xm.y), bf2f(xm.z), bf2f(xm.w)};
  const float a0[4] = {bf2f(x0.x), bf2f(x0.y), bf2f(x0.z), bf2f(x0.w)};
  const float ap[4] = {bf2f(xp.x), bf2f(xp.y), bf2f(xp.z), bf2f(xp.w)};
  float yq[4], yk[4], yv[4];
  float sq=0.f, ssq=0.f, sk=0.f, ssk=0.f, sv=0.f, ssv=0.f;
#pragma unroll
  for (int i = 0; i < 4; ++i){
    const float* qwp = qw + (c + i) * 3;
    const float* kwp = kw + (c + i) * 3;
    const float* vwp = vw + (c + i) * 3;
    const float q_ = (am[i]*qwp[0] + a0[i]*qwp[1] + ap[i]*qwp[2]) * mf;
    const float k_ = (am[i]*kwp[0] + a0[i]*kwp[1] + ap[i]*kwp[2]) * mf;
    const float v_ = (am[i]*vwp[0] + a0[i]*vwp[1] + ap[i]*vwp[2]) * mf;
    yq[i]=q_; yk[i]=k_; yv[i]=v_;
    sq+=q_; ssq+=q_*q_; sk+=k_; ssk+=k_*k_; sv+=v_; ssv+=v_*v_;
  }
  __shared__ float sb[24];
#pragma unroll
  for (int o = 1; o < 64; o <<= 1){
    sq += __shfl_xor(sq, o); ssq += __shfl_xor(ssq, o);
    sk += __shfl_xor(sk, o); ssk += __shfl_xor(ssk, o);
    sv += __shfl_xor(sv, o); ssv += __shfl_xor(ssv, o);
  }
  const int wid = tid >> 6, lane = tid & 63;
  if (lane == 0){
    sb[wid]=sq; sb[4+wid]=ssq; sb[8+wid]=sk; sb[12+wid]=ssk; sb[16+wid]=sv; sb[20+wid]=ssv;
  }
  __syncthreads();
  sq  = sb[0]+sb[1]+sb[2]+sb[3];    ssq = sb[4]+sb[5]+sb[6]+sb[7];
  sk  = sb[8]+sb[9]+sb[10]+sb[11];  ssk = sb[12]+sb[13]+sb[14]+sb[15];
  sv  = sb[16]+sb[17]+sb[18]+sb[19];ssv = sb[20]+sb[21]+sb[22]+sb[23];
  {
    const float mu = sq * (1.f/CC), rstd = rsqrtf(ssq*(1.f/CC) - mu*mu + EPSV);
    ushort4 p;
    p.x = f2bf((yq[0]-mu)*rstd*qg[c+0] + qb2[c+0]);
    p.y = f2bf((yq[1]-mu)*rstd*qg[c+1] + qb2[c+1]);
    p.z = f2bf((yq[2]-mu)*rstd*qg[c+2] + qb2[c+2]);
    p.w = f2bf((yq[3]-mu)*rstd*qg[c+3] + qb2[c+3]);
    *(ushort4*)(qn + (size_t)row * CC + c) = p;
  }
  {
    const float mu = sk * (1.f/CC), rstd = rsqrtf(ssk*(1.f/CC) - mu*mu + EPSV);
    ushort4 p;
    p.x = f2bf((yk[0]-mu)*rstd*kg[c+0] + kb2[c+0]);
    p.y = f2bf((yk[1]-mu)*rstd*kg[c+1] + kb2[c+1]);
    p.z = f2bf((yk[2]-mu)*rstd*kg[c+2] + kb2[c+2]);
    p.w = f2bf((yk[3]-mu)*rstd*kg[c+3] + kb2[c+3]);
    *(ushort4*)(kn + (size_t)row * CC + c) = p;
  }
  {
    const float mu = sv * (1.f/CC), rstd = rsqrtf(ssv*(1.f/CC) - mu*mu + EPSV);
    ushort4 p;
    p.x = f2bf((yv[0]-mu)*rstd*vg[c+0] + vb2[c+0]);
    p.y = f2bf((yv[1]-mu)*rstd*vg[c+1] + vb2[c+1]);
    p.z = f2bf((yv[2]-mu)*rstd*vg[c+2] + vb2[c+2]);
    p.w = f2bf((yv[3]-mu)*rstd*vg[c+3] + vb2[c+3]);
    *(ushort4*)(vn + (size_t)row * CC + c) = p;
  }
}

// ---------------- shared GEMM main loop v2: BK=64, double-buffered prefetch (T3 2-phase) ----------------
__device__ __forceinline__ void gemm_core(const u16* __restrict__ A, const u16* __restrict__ Bw,
    u16* As, u16* Bs, f32x4 acc[4][4], int bm, int bn, int tid){
  const int lane = tid & 63, wid = tid >> 6;
  const int wr = wid >> 1, wc = wid & 1;
  const int la = lane & 15, lg = lane >> 4;
  const int srow = tid >> 3;
  const int schunk = (tid & 7) ^ (srow & 7);
  const u16* gA = A  + (size_t)(bm * 128 + srow) * CC + schunk * 8;
  const u16* gB = Bw + (size_t)(bn * 128 + srow) * CC + schunk * 8;
  const int swz = (la & 7) << 4;
  auto stage = [&](int KT, int BUF){
    u16* dA = As + BUF * 8192 + tid * 8;
    u16* dB = Bs + BUF * 8192 + tid * 8;
#pragma unroll
    for (int i = 0; i < 4; ++i){
      gload_lds16(gA + (size_t)(i * 32) * CC + KT * 64, dA + i * 2048);
      gload_lds16(gB + (size_t)(i * 32) * CC + KT * 64, dB + i * 2048);
    }
  };
  stage(0, 0);
  __syncthreads();
  for (int kt = 0; kt < CC / 64; ++kt){
    const int cur = kt & 1;
    if (kt + 1 < CC / 64) stage(kt + 1, cur ^ 1);   // in flight across the compute phase
    const char* AsB = (const char*)(As + cur * 8192);
    const char* BsB = (const char*)(Bs + cur * 8192);
#pragma unroll
    for (int kk = 0; kk < 2; ++kk){
      bf16x8 af[4], bf[4];
      const int co = (kk * 64 + lg * 16) ^ swz;
#pragma unroll
      for (int mi = 0; mi < 4; ++mi)
        af[mi] = *(const bf16x8*)(AsB + (wr * 64 + mi * 16 + la) * 128 + co);
#pragma unroll
      for (int ni = 0; ni < 4; ++ni)
        bf[ni] = *(const bf16x8*)(BsB + (wc * 64 + ni * 16 + la) * 128 + co);
#pragma unroll
      for (int mi = 0; mi < 4; ++mi)
#pragma unroll
        for (int ni = 0; ni < 4; ++ni)
          acc[mi][ni] = __builtin_amdgcn_mfma_f32_16x16x32_bf16(af[mi], bf[ni], acc[mi][ni], 0, 0, 0);
    }
    __syncthreads();   // readers of buf[cur] done; stage into buf[cur^1] drained (vmcnt 0)
  }
}

// MODE 0: out bf16 (M,C).
// MODE 1: out bf16 = (acc+bias)*mask[m] + resid_f32[m,n]
// MODE 2: out f32  = acc + bias + resid_bf16[m,n]
template<int MODE>
__global__ __launch_bounds__(256, 2) void gemm_bt(
    const u16* __restrict__ A, const u16* __restrict__ Bw,
    const float* __restrict__ bias, void* __restrict__ out,
    const void* __restrict__ resid, const int* __restrict__ mask){
  __shared__ __align__(16) u16 As[2 * 8192];
  __shared__ __align__(16) u16 Bs[2 * 8192];
  const int tid = threadIdx.x, lane = tid & 63, wid = tid >> 6;
  const int wr = wid >> 1, wc = wid & 1;
  const int bm = blockIdx.x, bn = blockIdx.y;
  f32x4 acc[4][4];
#pragma unroll
  for (int i = 0; i < 4; ++i)
#pragma unroll
    for (int j = 0; j < 4; ++j) acc[i][j] = (f32x4){0.f, 0.f, 0.f, 0.f};
  gemm_core(A, Bw, As, Bs, acc, bm, bn, tid);
  const int la = lane & 15, lg = lane >> 4;
#pragma unroll
  for (int mi = 0; mi < 4; ++mi){
    const int mb = bm * 128 + wr * 64 + mi * 16 + lg * 4;
#pragma unroll
    for (int ni = 0; ni < 4; ++ni){
      const int n = bn * 128 + wc * 64 + ni * 16 + la;
      const float bz = bias[n];
      if (MODE == 0){
        u16* o = (u16*)out;
#pragma unroll
        for (int j = 0; j < 4; ++j) o[(size_t)(mb + j) * CC + n] = f2bf(acc[mi][ni][j] + bz);
      } else if (MODE == 1){
        u16* o = (u16*)out;
        const float* r = (const float*)resid;
#pragma unroll
        for (int j = 0; j < 4; ++j){
          const int m = mb + j;
          const float mf = mask[m] ? 1.f : 0.f;
          o[(size_t)m * CC + n] = f2bf((acc[mi][ni][j] + bz) * mf + r[(size_t)m * CC + n]);
        }
      } else {
        float* o = (float*)out;
        const u16* r = (const u16*)resid;
#pragma unroll
        for (int j = 0; j < 4; ++j){
          const int m = mb + j;
          o[(size_t)m * CC + n] = acc[mi][ni][j] + bz + bf2f(r[(size_t)m * CC + n]);
        }
      }
    }
  }
}

// fused q/k/v projection: z selects input/weight/bias/output; z==2 writes V transposed (B,H,D,T)
__global__ __launch_bounds__(256, 2) void gemm_qkv(
    const u16* __restrict__ qn, const u16* __restrict__ kn, const u16* __restrict__ vn,
    const u16* __restrict__ wq, const u16* __restrict__ wk, const u16* __restrict__ wv,
    const float* __restrict__ qb, const float* __restrict__ kb, const float* __restrict__ vb,
    u16* __restrict__ Qb, u16* __restrict__ Kb, u16* __restrict__ Vtb){
  __shared__ __align__(16) u16 As[2 * 8192];
  __shared__ __align__(16) u16 Bs[2 * 8192];
  const int z = blockIdx.z;
  const u16* A  = (z == 0) ? qn : (z == 1) ? kn : vn;
  const u16* Bw = (z == 0) ? wq : (z == 1) ? wk : wv;
  const float* bias = (z == 0) ? qb : (z == 1) ? kb : vb;
  const int tid = threadIdx.x, lane = tid & 63, wid = tid >> 6;
  const int wr = wid >> 1, wc = wid & 1;
  const int bm = blockIdx.x, bn = blockIdx.y;
  f32x4 acc[4][4];
#pragma unroll
  for (int i = 0; i < 4; ++i)
#pragma unroll
    for (int j = 0; j < 4; ++j) acc[i][j] = (f32x4){0.f, 0.f, 0.f, 0.f};
  gemm_core(A, Bw, As, Bs, acc, bm, bn, tid);
  const int la = lane & 15, lg = lane >> 4;
#pragma unroll
  for (int mi = 0; mi < 4; ++mi){
    const int mb = bm * 128 + wr * 64 + mi * 16 + lg * 4;
#pragma unroll
    for (int ni = 0; ni < 4; ++ni){
      const int n = bn * 128 + wc * 64 + ni * 16 + la;
      const float bz = bias[n];
      if (z < 2){
        u16* o = z ? Kb : Qb;
#pragma unroll
        for (int j = 0; j < 4; ++j) o[(size_t)(mb + j) * CC + n] = f2bf(acc[mi][ni][j] + bz);
      } else {
        const int bq = mb >> 11, tq = mb & (TT - 1);
        const int hq = n >> 8, dq = n & 255;
        ushort4 p;
        p.x = f2bf(acc[mi][ni][0] + bz); p.y = f2bf(acc[mi][ni][1] + bz);
        p.z = f2bf(acc[mi][ni][2] + bz); p.w = f2bf(acc[mi][ni][3] + bz);
        *(ushort4*)&Vtb[(size_t)((bq * HH + hq) * DD + dq) * TT + tq] = p;
      }
    }
  }
}

// ---------------- flash attention v10: v7 structure + balanced (h2,sp)-per-XCD mapping ----------------
// Wave = 32 q; block = 4 waves = 128 q; KVB=32; LDS 32KB; unnormalized partials + stats.
// XCD x handles (h2 = x>>1, sp = x&1) for ALL batches -> per-XCD work = sum_b len(b)/2 (balanced).
// D layout (m74/m101): col=lane&31 (=q), row=(reg&3)+8*(reg>>2)+4*(lane>>5) (=k or d).
__global__ __launch_bounds__(256, 2) void flash_attn(
    const u16* __restrict__ Q, const u16* __restrict__ Kg,
    const u16* __restrict__ Vt, const int* __restrict__ mask,
    u16* __restrict__ Os0, u16* __restrict__ Os1, float2* __restrict__ stats){
  __shared__ __align__(16) u16 Ks[32 * 256];   // 16KB: row k 512B, chunk ^= (r&7)
  __shared__ __align__(16) u16 Vs[256 * 32];   // 16KB: row d 64B, chunk ^= ((d>>1)&3)
  const int Dn = blockIdx.x;
  const int xcd = Dn & 7, rest = Dn >> 3;      // rest 0..63
  const int h2 = xcd >> 1, sp = xcd & 1;       // per-XCD: one head, one kv-split half, all batches
  const int b = rest >> 4, qt = rest & 15;     // 16 consecutive blocks share b (K/V L2 reuse)
  const int bh = b * HH + h2;
  const int tid = threadIdx.x, lane = tid & 63, wid = tid >> 6;
  const int l31 = lane & 31, hi = lane >> 5;

  // ---- sequence length via two ballot rounds (prefix mask, len in [1024,2048]) ----
  const int* mrow = mask + b * TT;
  int len = 1024;
  {
    unsigned long long bal = __ballot(mrow[1024 + lane * 16] != 0);
    int ones = __popcll(bal);
    if (ones > 0){
      int lo = 1024 + (ones - 1) * 16;
      unsigned long long bal2 = __ballot(mrow[lo + (lane & 15)] != 0);
      len = lo + __popcll(bal2 & 0xFFFFull);
    }
  }
  const int nkt = (len + 31) >> 5;
  const int hk = (nkt + 1) >> 1;
  const int t0 = sp ? hk : 0, t1 = sp ? nkt : hk;

  // ---- Q fragments: lane holds q = q0 + l31, d = kd*16 + hi*8 .. +8 ----
  const int q0 = qt * 128 + wid * 32;
  bf16x8 qf[16];
  const u16* qrow = Q + (size_t)(b * TT + q0 + l31) * CC + h2 * DD + hi * 8;
#pragma unroll
  for (int kd = 0; kd < 16; ++kd) qf[kd] = *(const bf16x8*)(qrow + kd * 16);

  f32x16 acc[8];
#pragma unroll
  for (int i = 0; i < 8; ++i)
#pragma unroll
    for (int r = 0; r < 16; ++r) acc[i][r] = 0.f;
  float mrun = NEGBIG, lrun = 0.f;

  // ---- staging (pre-swizzled global source, linear LDS dest) ----
  const int krow = tid >> 5;
  const int kc = (tid & 31) ^ (krow & 7);
  const u16* ksrc = Kg + (size_t)(b * TT + krow) * CC + h2 * DD + kc * 8;
  const int vc = (tid & 3) ^ ((tid >> 3) & 3);
  const u16* vsrcb = Vt + (size_t)(bh * DD + (tid >> 2)) * TT + vc * 8;

#define STAGE_K(KT) { _Pragma("unroll") \
  for (int i = 0; i < 4; ++i) \
    gload_lds16(ksrc + (size_t)((KT) * 32 + i * 8) * CC, Ks + i * 2048 + tid * 8); }
#define STAGE_V(KT) { _Pragma("unroll") \
  for (int i = 0; i < 4; ++i) \
    gload_lds16(vsrcb + (size_t)(i * 64) * TT + (KT) * 32, Vs + i * 2048 + tid * 8); }

  STAGE_K(t0); STAGE_V(t0);
  __syncthreads();

  const char* KsB = (const char*)Ks;
  const char* VsB = (const char*)Vs;
  const int swk = (l31 & 7) << 4;          // K read byte-XOR (row = l31)
  const int swv = ((l31 >> 1) & 3) << 4;   // V read byte-XOR (row = dt*32+l31)
  const float sc2 = SCALEV * 1.44269504f;  // softmax in exp2 domain

  for (int kt = t0; kt < t1; ++kt){
    // ---- QK^T: S^T(32k x 32q) = K_tile * Q^T over 16 d-slices ----
    f32x16 s;
#pragma unroll
    for (int r = 0; r < 16; ++r) s[r] = 0.f;
#pragma unroll
    for (int kd = 0; kd < 16; ++kd){
      bf16x8 kf = *(const bf16x8*)(KsB + l31 * 512 + ((kd * 32 + hi * 16) ^ swk));
      s = __builtin_amdgcn_mfma_f32_32x32x16_bf16(kf, qf[kd], s, 0, 0, 0);
    }
    // scale + tail mask: lane reg r -> k = kt*32 + (r&3) + 8*(r>>2) + 4*hi
    if (kt * 32 + 32 <= len){
      s *= sc2;
    } else {
#pragma unroll
      for (int r = 0; r < 16; ++r){
        const int k = kt * 32 + (r & 3) + 8 * (r >> 2) + 4 * hi;
        s[r] = (k < len) ? s[r] * sc2 : NEGBIG;
      }
    }
    // ---- online softmax: q = l31 lane-local; k-halves split across lane^32 ----
    float tm = s[0];
#pragma unroll
    for (int r = 1; r < 16; ++r) tm = fmaxf(tm, s[r]);
    tm = fmaxf(tm, __shfl_xor(tm, 32));
    if (!__all(tm <= mrun + 12.0f)){   // defer-max
      const float mn = fmaxf(mrun, tm);
      const float al = __builtin_exp2f(mrun - mn);
      mrun = mn; lrun *= al;
#pragma unroll
      for (int i = 0; i < 8; ++i) acc[i] *= al;
    }
    float p[16];
    float ts = 0.f;
#pragma unroll
    for (int r = 0; r < 16; ++r){ p[r] = __builtin_exp2f(s[r] - mrun); ts += p[r]; }
    ts += __shfl_xor(ts, 32);
    lrun += ts;
    // ---- pack P to bf16 pairs and build PV B-frags via permlane32_swap ----
    u32 w0 = cvtpk_bf16(p[0],  p[1]),  w1 = cvtpk_bf16(p[2],  p[3]);
    u32 w2 = cvtpk_bf16(p[4],  p[5]),  w3 = cvtpk_bf16(p[6],  p[7]);
    u32 w4 = cvtpk_bf16(p[8],  p[9]),  w5 = cvtpk_bf16(p[10], p[11]);
    u32 w6 = cvtpk_bf16(p[12], p[13]), w7 = cvtpk_bf16(p[14], p[15]);
    asm("v_permlane32_swap_b32 %0, %1" : "+v"(w0), "+v"(w2));
    asm("v_permlane32_swap_b32 %0, %1" : "+v"(w1), "+v"(w3));
    asm("v_permlane32_swap_b32 %0, %1" : "+v"(w4), "+v"(w6));
    asm("v_permlane32_swap_b32 %0, %1" : "+v"(w5), "+v"(w7));
    u32 pb0u[4] = {w0, w1, w2, w3};   // k = hi*8 + 0..7
    u32 pb1u[4] = {w4, w5, w6, w7};   // k = 16 + hi*8 + 0..7
    bf16x8 pb0 = __builtin_bit_cast(bf16x8, *(uint4*)pb0u);
    bf16x8 pb1 = __builtin_bit_cast(bf16x8, *(uint4*)pb1u);
    __syncthreads();   // b1: Ks readers done; V(kt) stage drained
    if (kt + 1 < t1) STAGE_K(kt + 1);   // hides under PV, drained at b2
    // ---- PV: O^T(d x q) += V^T_tile * P^T ----
#pragma unroll
    for (int dt = 0; dt < 8; ++dt){
      const char* vr = VsB + (dt * 32 + l31) * 64;
      bf16x8 vf0 = *(const bf16x8*)(vr + ((hi * 16) ^ swv));
      acc[dt] = __builtin_amdgcn_mfma_f32_32x32x16_bf16(vf0, pb0, acc[dt], 0, 0, 0);
      bf16x8 vf1 = *(const bf16x8*)(vr + ((32 + hi * 16) ^ swv));
      acc[dt] = __builtin_amdgcn_mfma_f32_32x32x16_bf16(vf1, pb1, acc[dt], 0, 0, 0);
    }
    __syncthreads();   // b2: Vs readers done; K(kt+1) stage drained
    if (kt + 1 < t1) STAGE_V(kt + 1);   // drained at next b1
  }
  // ---- epilogue: unnormalized partial O + (m,l) stats ----
  u16* Os = sp ? Os1 : Os0;
  u16* orow = Os + (size_t)(b * TT + q0 + l31) * CC + h2 * DD + hi * 4;
#pragma unroll
  for (int dt = 0; dt < 8; ++dt)
#pragma unroll
    for (int rg = 0; rg < 4; ++rg){
      ushort4 pk;
      pk.x = f2bf(acc[dt][rg * 4 + 0]); pk.y = f2bf(acc[dt][rg * 4 + 1]);
      pk.z = f2bf(acc[dt][rg * 4 + 2]); pk.w = f2bf(acc[dt][rg * 4 + 3]);
      *(ushort4*)(orow + dt * 32 + rg * 8) = pk;
    }
  if (lane < 32)
    stats[(size_t)((sp * 16 + bh) << 11) + q0 + l31] = make_float2(mrun, lrun);
#undef STAGE_K
#undef STAGE_V
}

// ---------------- combine the two kv-split partials ----------------
__global__ __launch_bounds__(256) void attn_combine(
    const u16* __restrict__ Os0, const u16* __restrict__ Os1,
    const float2* __restrict__ stats, u16* __restrict__ AO){
  const int row = blockIdx.x, tid = threadIdx.x;
  const int b = row >> 11, q = row & (TT - 1);
  const int h2 = tid >> 6;
  const int bh = b * HH + h2;
  const float2 sA = stats[(size_t)(bh << 11) + q];
  const float2 sB = stats[(size_t)((16 + bh) << 11) + q];
  const float m = fmaxf(sA.x, sB.x);
  const float eA = __builtin_exp2f(sA.x - m), eB = __builtin_exp2f(sB.x - m);
  const float l = sA.y * eA + sB.y * eB;
  const float fA = eA / l, fB = eB / l;
  const size_t off = (size_t)row * CC + tid * 4;
  const ushort4 a = *(const ushort4*)(Os0 + off);
  const ushort4 c = *(const ushort4*)(Os1 + off);
  ushort4 o;
  o.x = f2bf(bf2f(a.x) * fA + bf2f(c.x) * fB);
  o.y = f2bf(bf2f(a.y) * fA + bf2f(c.y) * fB);
  o.z = f2bf(bf2f(a.z) * fA + bf2f(c.z) * fB);
  o.w = f2bf(bf2f(a.w) * fA + bf2f(c.w) * fB);
  *(ushort4*)(AO + off) = o;
}

// ---------------- dwconv(tc) + bias + exact GELU ----------------
__global__ __launch_bounds__(256) void tc_gelu(const u16* __restrict__ y2,
    const float* __restrict__ w, const float* __restrict__ bias, u16* __restrict__ y3){
  const int row = blockIdx.x, tid = threadIdx.x;
  const int t = row & (TT - 1);
  const int c = tid * 4;
  ushort4 z4; z4.x = z4.y = z4.z = z4.w = 0;
  const ushort4 u0 = *(const ushort4*)(y2 + (size_t)row * CC + c);
  const ushort4 um = (t > 0)      ? *(const ushort4*)(y2 + (size_t)(row - 1) * CC + c) : z4;
  const ushort4 up = (t < TT - 1) ? *(const ushort4*)(y2 + (size_t)(row + 1) * CC + c) : z4;
  const float am[4] = {bf2f(um.x), bf2f(um.y), bf2f(um.z), bf2f(um.w)};
  const float a0[4] = {bf2f(u0.x), bf2f(u0.y), bf2f(u0.z), bf2f(u0.w)};
  const float ap[4] = {bf2f(up.x), bf2f(up.y), bf2f(up.z), bf2f(up.w)};
  u16 pv[4];
#pragma unroll
  for (int i = 0; i < 4; ++i){
    const float* wp = w + (c + i) * 3;
    const float yv = am[i] * wp[0] + a0[i] * wp[1] + ap[i] * wp[2] + bias[c + i];
    const float ge = 0.5f * yv * (1.f + erff(yv * 0.7071067811865475f));
    pv[i] = f2bf(ge);
  }
  ushort4 p; p.x = pv[0]; p.y = pv[1]; p.z = pv[2]; p.w = pv[3];
  *(ushort4*)(y3 + (size_t)row * CC + c) = p;
}

extern "C" void kernel_launch(void* const* d_in, const int* in_sizes, int n_in,
                              void* d_out, int out_size, void* d_ws, size_t ws_size,
                              hipStream_t stream){
  const float* x     = (const float*)d_in[0];
  const int*   mask  = (const int*)d_in[1];
  const float* n1g   = (const float*)d_in[2];
  const float* n1b   = (const float*)d_in[3];
  const float* qconv = (const float*)d_in[4];
  const float* kconv = (const float*)d_in[5];
  const float* vconv = (const float*)d_in[6];
  const float* qg    = (const float*)d_in[7];
  const float* qbe   = (const float*)d_in[8];
  const float* kg    = (const float*)d_in[9];
  const float* kbe   = (const float*)d_in[10];
  const float* vg    = (const float*)d_in[11];
  const float* vbe   = (const float*)d_in[12];
  const float* q1w   = (const float*)d_in[13];
  const float* q1b   = (const float*)d_in[14];
  const float* k1w   = (const float*)d_in[15];
  const float* k1b   = (const float*)d_in[16];
  const float* v1w   = (const float*)d_in[17];
  const float* v1b   = (const float*)d_in[18];
  const float* pw    = (const float*)d_in[19];
  const float* pb    = (const float*)d_in[20];
  const float* n2g   = (const float*)d_in[21];
  const float* n2b   = (const float*)d_in[22];
  const float* l1w   = (const float*)d_in[23];
  const float* l1b   = (const float*)d_in[24];
  const float* tcw   = (const float*)d_in[25];
  const float* tcb   = (const float*)d_in[26];
  const float* l2w   = (const float*)d_in[27];
  const float* l2b   = (const float*)d_in[28];
  (void)in_sizes; (void)n_in; (void)out_size; (void)ws_size;

  char* ws = (char*)d_ws;
  const size_t MB = (size_t)1 << 20;
  u16* wq  = (u16*)(ws + 0 * MB);
  u16* wk  = (u16*)(ws + 2 * MB);
  u16* wv  = (u16*)(ws + 4 * MB);
  u16* wp2 = (u16*)(ws + 6 * MB);
  u16* wl1 = (u16*)(ws + 8 * MB);
  u16* wl2 = (u16*)(ws + 10 * MB);
  u16* hbuf = (u16*)(ws + 12 * MB);   // 16 MB bf16 LN1 output; dead after qkv_pre
  u16* x2b  = (u16*)(ws + 12 * MB);   // 16 MB bf16 residual stream; written after hbuf dead
  u16* qn  = (u16*)(ws + 44 * MB);
  u16* kn  = (u16*)(ws + 60 * MB);
  u16* vn  = (u16*)(ws + 76 * MB);
  u16* Qb  = (u16*)(ws + 92 * MB);
  u16* Kb  = (u16*)(ws + 108 * MB);
  u16* Vtb = (u16*)(ws + 124 * MB);
  float2* stats = (float2*)(ws + 140 * MB);   // 512 KB
  u16* AO  = qn;    // attnout  (qn dead after qkv GEMM)
  u16* Os0 = kn;    // kv-split partial 0 (kn dead after qkv GEMM)
  u16* Os1 = vn;    // kv-split partial 1 (vn dead after qkv GEMM)
  u16* y1  = kn;    // LN2 out  (Os0 dead after combine)
  u16* y2  = vn;    // lin1 out (Os1 dead after combine)
  u16* y3  = Qb;    // gelu out (Q dead after flash)

  conv_w_kernel<<<1024, 256, 0, stream>>>(q1w, k1w, v1w, pw, l1w, l2w, wq, wk, wv, wp2, wl1, wl2);
  ln_rows<<<MM, 256, 0, stream>>>(x, n1g, n1b, hbuf);
  qkv_pre<<<MM, 256, 0, stream>>>(hbuf, mask, qconv, kconv, vconv,
                                  qg, qbe, kg, kbe, vg, vbe, qn, kn, vn);
  gemm_qkv<<<dim3(64, 8, 3), 256, 0, stream>>>(qn, kn, vn, wq, wk, wv, q1b, k1b, v1b, Qb, Kb, Vtb);
  flash_attn<<<512, 256, 0, stream>>>(Qb, Kb, Vtb, mask, Os0, Os1, stats);
  attn_combine<<<MM, 256, 0, stream>>>(Os0, Os1, stats, AO);
  gemm_bt<1><<<dim3(64, 8), 256, 0, stream>>>(AO, wp2, pb, x2b, x, mask);
  ln_rows_b2b<<<MM, 256, 0, stream>>>(x2b, n2g, n2b, y1);
  gemm_bt<0><<<dim3(64, 8), 256, 0, stream>>>(y1, wl1, l1b, y2, nullptr, nullptr);
  tc_gelu<<<MM, 256, 0, stream>>>(y2, tcw, tcb, y3);
  gemm_bt<2><<<dim3(64, 8), 256, 0, stream>>>(y3, wl2, l2b, (float*)d_out, x2b, nullptr);
}

// Round 18
// 309.672 us; speedup vs baseline: 3.4515x; 1.0092x over previous
//
#include <hip/hip_runtime.h>

#define BB 4
#define TT 2048
#define CC 1024
#define HH 4
#define DD 256
#define MM (BB*TT)

#define EPSV 1e-5f
#define NEGBIG (-1e30f)
#define SCALEV 0.0625f   // 1/sqrt(256)

typedef unsigned short u16;
typedef unsigned int   u32;
typedef __bf16 bf16x8 __attribute__((ext_vector_type(8)));
typedef float  f32x4  __attribute__((ext_vector_type(4)));
typedef float  f32x16 __attribute__((ext_vector_type(16)));

typedef u32 __attribute__((address_space(1))) gu32;
typedef u32 __attribute__((address_space(3))) lu32;

__device__ __forceinline__ u16 f2bf(float f){
  u32 u = __builtin_bit_cast(u32, f);
  u32 r = (u + 0x7fffu + ((u >> 16) & 1u)) >> 16;
  return (u16)r;
}
__device__ __forceinline__ float bf2f(u16 h){
  u32 u = ((u32)h) << 16;
  return __builtin_bit_cast(float, u);
}
__device__ __forceinline__ void gload_lds16(const u16* g, u16* l){
  __builtin_amdgcn_global_load_lds((const gu32*)g, (lu32*)l, 16, 0, 0);
}
__device__ __forceinline__ u32 cvtpk_bf16(float lo, float hi){
  u32 r;
  asm("v_cvt_pk_bf16_f32 %0, %1, %2" : "=v"(r) : "v"(lo), "v"(hi));
  return r;
}

// ---------------- channel LayerNorm (f32 in, bf16 out) + fused weight f32->bf16 conversion ----------------
// Blocks 0..1023 additionally convert the six CxC weight matrices to bf16 (independent work,
// previously a separate dispatch; fused to save a launch + gap).
__global__ __launch_bounds__(256) void ln_rows_w(const float* __restrict__ x,
    const float* __restrict__ g, const float* __restrict__ be, u16* __restrict__ out,
    const float* __restrict__ w0, const float* __restrict__ w1, const float* __restrict__ w2,
    const float* __restrict__ w3, const float* __restrict__ w4, const float* __restrict__ w5,
    u16* __restrict__ o0, u16* __restrict__ o1, u16* __restrict__ o2,
    u16* __restrict__ o3, u16* __restrict__ o4, u16* __restrict__ o5){
  const int row = blockIdx.x, tid = threadIdx.x;
  if (row < 1024){
    const int i = (row * 256 + tid) * 4;
    const float* wsrc[6] = {w0,w1,w2,w3,w4,w5};
    u16* odst[6] = {o0,o1,o2,o3,o4,o5};
#pragma unroll
    for (int k = 0; k < 6; ++k){
      float4 v = *(const float4*)(wsrc[k] + i);
      ushort4 p; p.x=f2bf(v.x); p.y=f2bf(v.y); p.z=f2bf(v.z); p.w=f2bf(v.w);
      *(ushort4*)(odst[k] + i) = p;
    }
  }
  const float4 v = ((const float4*)(x + (size_t)row * CC))[tid];
  float s  = v.x + v.y + v.z + v.w;
  float ss = v.x*v.x + v.y*v.y + v.z*v.z + v.w*v.w;
  __shared__ float sb[8];
#pragma unroll
  for (int o = 1; o < 64; o <<= 1){ s += __shfl_xor(s, o); ss += __shfl_xor(ss, o); }
  const int wid = tid >> 6, lane = tid & 63;
  if (lane == 0){ sb[wid] = s; sb[4 + wid] = ss; }
  __syncthreads();
  s  = sb[0] + sb[1] + sb[2] + sb[3];
  ss = sb[4] + sb[5] + sb[6] + sb[7];
  const float mu = s * (1.0f / CC);
  const float rstd = rsqrtf(ss * (1.0f / CC) - mu * mu + EPSV);
  const float4 gg = ((const float4*)g)[tid];
  const float4 bb = ((const float4*)be)[tid];
  ushort4 p;
  p.x = f2bf((v.x - mu) * rstd * gg.x + bb.x);
  p.y = f2bf((v.y - mu) * rstd * gg.y + bb.y);
  p.z = f2bf((v.z - mu) * rstd * gg.z + bb.z);
  p.w = f2bf((v.w - mu) * rstd * gg.w + bb.w);
  *(ushort4*)(out + (size_t)row * CC + tid * 4) = p;
}

// ---------------- channel LayerNorm, bf16 in -> bf16 out ----------------
__global__ __launch_bounds__(256) void ln_rows_b2b(const u16* __restrict__ x,
    const float* __restrict__ g, const float* __restrict__ be, u16* __restrict__ out){
  const int row = blockIdx.x, tid = threadIdx.x;
  const ushort4 u = ((const ushort4*)(x + (size_t)row * CC))[tid];
  const float v0 = bf2f(u.x), v1 = bf2f(u.y), v2 = bf2f(u.z), v3 = bf2f(u.w);
  float s  = v0 + v1 + v2 + v3;
  float ss = v0*v0 + v1*v1 + v2*v2 + v3*v3;
  __shared__ float sb[8];
#pragma unroll
  for (int o = 1; o < 64; o <<= 1){ s += __shfl_xor(s, o); ss += __shfl_xor(ss, o); }
  const int wid = tid >> 6, lane = tid & 63;
  if (lane == 0){ sb[wid] = s; sb[4 + wid] = ss; }
  __syncthreads();
  s  = sb[0] + sb[1] + sb[2] + sb[3];
  ss = sb[4] + sb[5] + sb[6] + sb[7];
  const float mu = s * (1.0f / CC);
  const float rstd = rsqrtf(ss * (1.0f / CC) - mu * mu + EPSV);
  const float4 gg = ((const float4*)g)[tid];
  const float4 bb = ((const float4*)be)[tid];
  ushort4 p;
  p.x = f2bf((v0 - mu) * rstd * gg.x + bb.x);
  p.y = f2bf((v1 - mu) * rstd * gg.y + bb.y);
  p.z = f2bf((v2 - mu) * rstd * gg.z + bb.z);
  p.w = f2bf((v3 - mu) * rstd * gg.w + bb.w);
  *(ushort4*)(out + (size_t)row * CC + tid * 4) = p;
}

// ------------ fused q/k/v: dwconv3 (pad1) * mask -> LN -> bf16 (bf16 input h) ------------
__global__ __launch_bounds__(256) void qkv_pre(const u16* __restrict__ h,
    const int* __restrict__ mask,
    const float* __restrict__ qw, const float* __restrict__ kw, const float* __restrict__ vw,
    const float* __restrict__ qg, const float* __restrict__ qb2,
    const float* __restrict__ kg, const float* __restrict__ kb2,
    const float* __restrict__ vg, const float* __restrict__ vb2,
    u16* __restrict__ qn, u16* __restrict__ kn, u16* __restrict__ vn){
  const int row = blockIdx.x, tid = threadIdx.x;
  const int t = row & (TT - 1);
  const float mf = mask[row] ? 1.f : 0.f;
  ushort4 z4; z4.x = z4.y = z4.z = z4.w = 0;
  const ushort4 x0 = ((const ushort4*)(h + (size_t)row * CC))[tid];
  const ushort4 xm = (t > 0)      ? ((const ushort4*)(h + (size_t)(row - 1) * CC))[tid] : z4;
  const ushort4 xp = (t < TT - 1) ? ((const ushort4*)(h + (size_t)(row + 1) * CC))[tid] : z4;
  const int c = tid * 4;
  const float am[4] = {bf2f(xm.x), bf2f(xm.y), bf2f(xm.z), bf2f(xm.w)};
  const float a0[4] = {bf2f(x0.x), bf2f(x0.y), bf2f(x0.z), bf2f(x0.w)};
  const float ap[4] = {bf2f(xp.x), bf2f(xp.y), bf2f(xp.z), bf2f(xp.w)};
  float yq[4], yk[4], yv[4];
  float sq=0.f, ssq=0.f, sk=0.f, ssk=0.f, sv=0.f, ssv=0.f;
#pragma unroll
  for (int i = 0; i < 4; ++i){
    const float* qwp = qw + (c + i) * 3;
    const float* kwp = kw + (c + i) * 3;
    const float* vwp = vw + (c + i) * 3;
    const float q_ = (am[i]*qwp[0] + a0[i]*qwp[1] + ap[i]*qwp[2]) * mf;
    const float k_ = (am[i]*kwp[0] + a0[i]*kwp[1] + ap[i]*kwp[2]) * mf;
    const float v_ = (am[i]*vwp[0] + a0[i]*vwp[1] + ap[i]*vwp[2]) * mf;
    yq[i]=q_; yk[i]=k_; yv[i]=v_;
    sq+=q_; ssq+=q_*q_; sk+=k_; ssk+=k_*k_; sv+=v_; ssv+=v_*v_;
  }
  __shared__ float sb[24];
#pragma unroll
  for (int o = 1; o < 64; o <<= 1){
    sq += __shfl_xor(sq, o); ssq += __shfl_xor(ssq, o);
    sk += __shfl_xor(sk, o); ssk += __shfl_xor(ssk, o);
    sv += __shfl_xor(sv, o); ssv += __shfl_xor(ssv, o);
  }
  const int wid = tid >> 6, lane = tid & 63;
  if (lane == 0){
    sb[wid]=sq; sb[4+wid]=ssq; sb[8+wid]=sk; sb[12+wid]=ssk; sb[16+wid]=sv; sb[20+wid]=ssv;
  }
  __syncthreads();
  sq  = sb[0]+sb[1]+sb[2]+sb[3];    ssq = sb[4]+sb[5]+sb[6]+sb[7];
  sk  = sb[8]+sb[9]+sb[10]+sb[11];  ssk = sb[12]+sb[13]+sb[14]+sb[15];
  sv  = sb[16]+sb[17]+sb[18]+sb[19];ssv = sb[20]+sb[21]+sb[22]+sb[23];
  {
    const float mu = sq * (1.f/CC), rstd = rsqrtf(ssq*(1.f/CC) - mu*mu + EPSV);
    ushort4 p;
    p.x = f2bf((yq[0]-mu)*rstd*qg[c+0] + qb2[c+0]);
    p.y = f2bf((yq[1]-mu)*rstd*qg[c+1] + qb2[c+1]);
    p.z = f2bf((yq[2]-mu)*rstd*qg[c+2] + qb2[c+2]);
    p.w = f2bf((yq[3]-mu)*rstd*qg[c+3] + qb2[c+3]);
    *(ushort4*)(qn + (size_t)row * CC + c) = p;
  }
  {
    const float mu = sk * (1.f/CC), rstd = rsqrtf(ssk*(1.f/CC) - mu*mu + EPSV);
    ushort4 p;
    p.x = f2bf((yk[0]-mu)*rstd*kg[c+0] + kb2[c+0]);
    p.y = f2bf((yk[1]-mu)*rstd*kg[c+1] + kb2[c+1]);
    p.z = f2bf((yk[2]-mu)*rstd*kg[c+2] + kb2[c+2]);
    p.w = f2bf((yk[3]-mu)*rstd*kg[c+3] + kb2[c+3]);
    *(ushort4*)(kn + (size_t)row * CC + c) = p;
  }
  {
    const float mu = sv * (1.f/CC), rstd = rsqrtf(ssv*(1.f/CC) - mu*mu + EPSV);
    ushort4 p;
    p.x = f2bf((yv[0]-mu)*rstd*vg[c+0] + vb2[c+0]);
    p.y = f2bf((yv[1]-mu)*rstd*vg[c+1] + vb2[c+1]);
    p.z = f2bf((yv[2]-mu)*rstd*vg[c+2] + vb2[c+2]);
    p.w = f2bf((yv[3]-mu)*rstd*vg[c+3] + vb2[c+3]);
    *(ushort4*)(vn + (size_t)row * CC + c) = p;
  }
}

// ---------------- shared GEMM main loop v2: BK=64, double-buffered prefetch (T3 2-phase) ----------------
__device__ __forceinline__ void gemm_core(const u16* __restrict__ A, const u16* __restrict__ Bw,
    u16* As, u16* Bs, f32x4 acc[4][4], int bm, int bn, int tid){
  const int lane = tid & 63, wid = tid >> 6;
  const int wr = wid >> 1, wc = wid & 1;
  const int la = lane & 15, lg = lane >> 4;
  const int srow = tid >> 3;
  const int schunk = (tid & 7) ^ (srow & 7);
  const u16* gA = A  + (size_t)(bm * 128 + srow) * CC + schunk * 8;
  const u16* gB = Bw + (size_t)(bn * 128 + srow) * CC + schunk * 8;
  const int swz = (la & 7) << 4;
  auto stage = [&](int KT, int BUF){
    u16* dA = As + BUF * 8192 + tid * 8;
    u16* dB = Bs + BUF * 8192 + tid * 8;
#pragma unroll
    for (int i = 0; i < 4; ++i){
      gload_lds16(gA + (size_t)(i * 32) * CC + KT * 64, dA + i * 2048);
      gload_lds16(gB + (size_t)(i * 32) * CC + KT * 64, dB + i * 2048);
    }
  };
  stage(0, 0);
  __syncthreads();
  for (int kt = 0; kt < CC / 64; ++kt){
    const int cur = kt & 1;
    if (kt + 1 < CC / 64) stage(kt + 1, cur ^ 1);   // in flight across the compute phase
    const char* AsB = (const char*)(As + cur * 8192);
    const char* BsB = (const char*)(Bs + cur * 8192);
#pragma unroll
    for (int kk = 0; kk < 2; ++kk){
      bf16x8 af[4], bf[4];
      const int co = (kk * 64 + lg * 16) ^ swz;
#pragma unroll
      for (int mi = 0; mi < 4; ++mi)
        af[mi] = *(const bf16x8*)(AsB + (wr * 64 + mi * 16 + la) * 128 + co);
#pragma unroll
      for (int ni = 0; ni < 4; ++ni)
        bf[ni] = *(const bf16x8*)(BsB + (wc * 64 + ni * 16 + la) * 128 + co);
#pragma unroll
      for (int mi = 0; mi < 4; ++mi)
#pragma unroll
        for (int ni = 0; ni < 4; ++ni)
          acc[mi][ni] = __builtin_amdgcn_mfma_f32_16x16x32_bf16(af[mi], bf[ni], acc[mi][ni], 0, 0, 0);
    }
    __syncthreads();   // readers of buf[cur] done; stage into buf[cur^1] drained (vmcnt 0)
  }
}

// MODE 0: out bf16 (M,C).
// MODE 1: out bf16 = (acc+bias)*mask[m] + resid_f32[m,n]
// MODE 2: out f32  = acc + bias + resid_bf16[m,n]
template<int MODE>
__global__ __launch_bounds__(256, 2) void gemm_bt(
    const u16* __restrict__ A, const u16* __restrict__ Bw,
    const float* __restrict__ bias, void* __restrict__ out,
    const void* __restrict__ resid, const int* __restrict__ mask){
  __shared__ __align__(16) u16 As[2 * 8192];
  __shared__ __align__(16) u16 Bs[2 * 8192];
  const int tid = threadIdx.x, lane = tid & 63, wid = tid >> 6;
  const int wr = wid >> 1, wc = wid & 1;
  const int bm = blockIdx.x, bn = blockIdx.y;
  f32x4 acc[4][4];
#pragma unroll
  for (int i = 0; i < 4; ++i)
#pragma unroll
    for (int j = 0; j < 4; ++j) acc[i][j] = (f32x4){0.f, 0.f, 0.f, 0.f};
  gemm_core(A, Bw, As, Bs, acc, bm, bn, tid);
  const int la = lane & 15, lg = lane >> 4;
#pragma unroll
  for (int mi = 0; mi < 4; ++mi){
    const int mb = bm * 128 + wr * 64 + mi * 16 + lg * 4;
#pragma unroll
    for (int ni = 0; ni < 4; ++ni){
      const int n = bn * 128 + wc * 64 + ni * 16 + la;
      const float bz = bias[n];
      if (MODE == 0){
        u16* o = (u16*)out;
#pragma unroll
        for (int j = 0; j < 4; ++j) o[(size_t)(mb + j) * CC + n] = f2bf(acc[mi][ni][j] + bz);
      } else if (MODE == 1){
        u16* o = (u16*)out;
        const float* r = (const float*)resid;
#pragma unroll
        for (int j = 0; j < 4; ++j){
          const int m = mb + j;
          const float mf = mask[m] ? 1.f : 0.f;
          o[(size_t)m * CC + n] = f2bf((acc[mi][ni][j] + bz) * mf + r[(size_t)m * CC + n]);
        }
      } else {
        float* o = (float*)out;
        const u16* r = (const u16*)resid;
#pragma unroll
        for (int j = 0; j < 4; ++j){
          const int m = mb + j;
          o[(size_t)m * CC + n] = acc[mi][ni][j] + bz + bf2f(r[(size_t)m * CC + n]);
        }
      }
    }
  }
}

// fused q/k/v projection: z selects input/weight/bias/output; z==2 writes V transposed (B,H,D,T)
__global__ __launch_bounds__(256, 2) void gemm_qkv(
    const u16* __restrict__ qn, const u16* __restrict__ kn, const u16* __restrict__ vn,
    const u16* __restrict__ wq, const u16* __restrict__ wk, const u16* __restrict__ wv,
    const float* __restrict__ qb, const float* __restrict__ kb, const float* __restrict__ vb,
    u16* __restrict__ Qb, u16* __restrict__ Kb, u16* __restrict__ Vtb){
  __shared__ __align__(16) u16 As[2 * 8192];
  __shared__ __align__(16) u16 Bs[2 * 8192];
  const int z = blockIdx.z;
  const u16* A  = (z == 0) ? qn : (z == 1) ? kn : vn;
  const u16* Bw = (z == 0) ? wq : (z == 1) ? wk : wv;
  const float* bias = (z == 0) ? qb : (z == 1) ? kb : vb;
  const int tid = threadIdx.x, lane = tid & 63, wid = tid >> 6;
  const int wr = wid >> 1, wc = wid & 1;
  const int bm = blockIdx.x, bn = blockIdx.y;
  f32x4 acc[4][4];
#pragma unroll
  for (int i = 0; i < 4; ++i)
#pragma unroll
    for (int j = 0; j < 4; ++j) acc[i][j] = (f32x4){0.f, 0.f, 0.f, 0.f};
  gemm_core(A, Bw, As, Bs, acc, bm, bn, tid);
  const int la = lane & 15, lg = lane >> 4;
#pragma unroll
  for (int mi = 0; mi < 4; ++mi){
    const int mb = bm * 128 + wr * 64 + mi * 16 + lg * 4;
#pragma unroll
    for (int ni = 0; ni < 4; ++ni){
      const int n = bn * 128 + wc * 64 + ni * 16 + la;
      const float bz = bias[n];
      if (z < 2){
        u16* o = z ? Kb : Qb;
#pragma unroll
        for (int j = 0; j < 4; ++j) o[(size_t)(mb + j) * CC + n] = f2bf(acc[mi][ni][j] + bz);
      } else {
        const int bq = mb >> 11, tq = mb & (TT - 1);
        const int hq = n >> 8, dq = n & 255;
        ushort4 p;
        p.x = f2bf(acc[mi][ni][0] + bz); p.y = f2bf(acc[mi][ni][1] + bz);
        p.z = f2bf(acc[mi][ni][2] + bz); p.w = f2bf(acc[mi][ni][3] + bz);
        *(ushort4*)&Vtb[(size_t)((bq * HH + hq) * DD + dq) * TT + tq] = p;
      }
    }
  }
}

// ---------------- flash attention v10: 32x32x16, register P, kv-split=2, balanced XCD map ----------------
// Wave = 32 q; block = 4 waves = 128 q; KVB=32; LDS 32KB; unnormalized partials + stats.
// XCD x handles (h2 = x>>1, sp = x&1) for ALL batches -> per-XCD work = sum_b len(b)/2 (balanced).
// D layout (m74/m101): col=lane&31 (=q), row=(reg&3)+8*(reg>>2)+4*(lane>>5) (=k or d).
__global__ __launch_bounds__(256, 2) void flash_attn(
    const u16* __restrict__ Q, const u16* __restrict__ Kg,
    const u16* __restrict__ Vt, const int* __restrict__ mask,
    u16* __restrict__ Os0, u16* __restrict__ Os1, float2* __restrict__ stats){
  __shared__ __align__(16) u16 Ks[32 * 256];   // 16KB: row k 512B, chunk ^= (r&7)
  __shared__ __align__(16) u16 Vs[256 * 32];   // 16KB: row d 64B, chunk ^= ((d>>1)&3)
  const int Dn = blockIdx.x;
  const int xcd = Dn & 7, rest = Dn >> 3;      // rest 0..63
  const int h2 = xcd >> 1, sp = xcd & 1;       // per-XCD: one head, one kv-split half, all batches
  const int b = rest >> 4, qt = rest & 15;     // 16 consecutive blocks share b (K/V L2 reuse)
  const int bh = b * HH + h2;
  const int tid = threadIdx.x, lane = tid & 63, wid = tid >> 6;
  const int l31 = lane & 31, hi = lane >> 5;

  // ---- sequence length via two ballot rounds (prefix mask, len in [1024,2048]) ----
  const int* mrow = mask + b * TT;
  int len = 1024;
  {
    unsigned long long bal = __ballot(mrow[1024 + lane * 16] != 0);
    int ones = __popcll(bal);
    if (ones > 0){
      int lo = 1024 + (ones - 1) * 16;
      unsigned long long bal2 = __ballot(mrow[lo + (lane & 15)] != 0);
      len = lo + __popcll(bal2 & 0xFFFFull);
    }
  }
  const int nkt = (len + 31) >> 5;
  const int hk = (nkt + 1) >> 1;
  const int t0 = sp ? hk : 0, t1 = sp ? nkt : hk;

  // ---- Q fragments: lane holds q = q0 + l31, d = kd*16 + hi*8 .. +8 ----
  const int q0 = qt * 128 + wid * 32;
  bf16x8 qf[16];
  const u16* qrow = Q + (size_t)(b * TT + q0 + l31) * CC + h2 * DD + hi * 8;
#pragma unroll
  for (int kd = 0; kd < 16; ++kd) qf[kd] = *(const bf16x8*)(qrow + kd * 16);

  f32x16 acc[8];
#pragma unroll
  for (int i = 0; i < 8; ++i)
#pragma unroll
    for (int r = 0; r < 16; ++r) acc[i][r] = 0.f;
  float mrun = NEGBIG, lrun = 0.f;

  // ---- staging (pre-swizzled global source, linear LDS dest) ----
  const int krow = tid >> 5;
  const int kc = (tid & 31) ^ (krow & 7);
  const u16* ksrc = Kg + (size_t)(b * TT + krow) * CC + h2 * DD + kc * 8;
  const int vc = (tid & 3) ^ ((tid >> 3) & 3);
  const u16* vsrcb = Vt + (size_t)(bh * DD + (tid >> 2)) * TT + vc * 8;

#define STAGE_K(KT) { _Pragma("unroll") \
  for (int i = 0; i < 4; ++i) \
    gload_lds16(ksrc + (size_t)((KT) * 32 + i * 8) * CC, Ks + i * 2048 + tid * 8); }
#define STAGE_V(KT) { _Pragma("unroll") \
  for (int i = 0; i < 4; ++i) \
    gload_lds16(vsrcb + (size_t)(i * 64) * TT + (KT) * 32, Vs + i * 2048 + tid * 8); }

  STAGE_K(t0); STAGE_V(t0);
  __syncthreads();

  const char* KsB = (const char*)Ks;
  const char* VsB = (const char*)Vs;
  const int swk = (l31 & 7) << 4;          // K read byte-XOR (row = l31)
  const int swv = ((l31 >> 1) & 3) << 4;   // V read byte-XOR (row = dt*32+l31)
  const float sc2 = SCALEV * 1.44269504f;  // softmax in exp2 domain

  for (int kt = t0; kt < t1; ++kt){
    // ---- QK^T: S^T(32k x 32q) = K_tile * Q^T over 16 d-slices ----
    f32x16 s;
#pragma unroll
    for (int r = 0; r < 16; ++r) s[r] = 0.f;
#pragma unroll
    for (int kd = 0; kd < 16; ++kd){
      bf16x8 kf = *(const bf16x8*)(KsB + l31 * 512 + ((kd * 32 + hi * 16) ^ swk));
      s = __builtin_amdgcn_mfma_f32_32x32x16_bf16(kf, qf[kd], s, 0, 0, 0);
    }
    // scale + tail mask: lane reg r -> k = kt*32 + (r&3) + 8*(r>>2) + 4*hi
    if (kt * 32 + 32 <= len){
      s *= sc2;
    } else {
#pragma unroll
      for (int r = 0; r < 16; ++r){
        const int k = kt * 32 + (r & 3) + 8 * (r >> 2) + 4 * hi;
        s[r] = (k < len) ? s[r] * sc2 : NEGBIG;
      }
    }
    // ---- online softmax: q = l31 lane-local; k-halves split across lane^32 ----
    float tm = s[0];
#pragma unroll
    for (int r = 1; r < 16; ++r) tm = fmaxf(tm, s[r]);
    tm = fmaxf(tm, __shfl_xor(tm, 32));
    if (!__all(tm <= mrun + 12.0f)){   // defer-max
      const float mn = fmaxf(mrun, tm);
      const float al = __builtin_exp2f(mrun - mn);
      mrun = mn; lrun *= al;
#pragma unroll
      for (int i = 0; i < 8; ++i) acc[i] *= al;
    }
    float p[16];
    float ts = 0.f;
#pragma unroll
    for (int r = 0; r < 16; ++r){ p[r] = __builtin_exp2f(s[r] - mrun); ts += p[r]; }
    ts += __shfl_xor(ts, 32);
    lrun += ts;
    // ---- pack P to bf16 pairs and build PV B-frags via permlane32_swap ----
    u32 w0 = cvtpk_bf16(p[0],  p[1]),  w1 = cvtpk_bf16(p[2],  p[3]);
    u32 w2 = cvtpk_bf16(p[4],  p[5]),  w3 = cvtpk_bf16(p[6],  p[7]);
    u32 w4 = cvtpk_bf16(p[8],  p[9]),  w5 = cvtpk_bf16(p[10], p[11]);
    u32 w6 = cvtpk_bf16(p[12], p[13]), w7 = cvtpk_bf16(p[14], p[15]);
    asm("v_permlane32_swap_b32 %0, %1" : "+v"(w0), "+v"(w2));
    asm("v_permlane32_swap_b32 %0, %1" : "+v"(w1), "+v"(w3));
    asm("v_permlane32_swap_b32 %0, %1" : "+v"(w4), "+v"(w6));
    asm("v_permlane32_swap_b32 %0, %1" : "+v"(w5), "+v"(w7));
    u32 pb0u[4] = {w0, w1, w2, w3};   // k = hi*8 + 0..7
    u32 pb1u[4] = {w4, w5, w6, w7};   // k = 16 + hi*8 + 0..7
    bf16x8 pb0 = __builtin_bit_cast(bf16x8, *(uint4*)pb0u);
    bf16x8 pb1 = __builtin_bit_cast(bf16x8, *(uint4*)pb1u);
    __syncthreads();   // b1: Ks readers done; V(kt) stage drained
    if (kt + 1 < t1) STAGE_K(kt + 1);   // hides under PV, drained at b2
    // ---- PV: O^T(d x q) += V^T_tile * P^T ----
#pragma unroll
    for (int dt = 0; dt < 8; ++dt){
      const char* vr = VsB + (dt * 32 + l31) * 64;
      bf16x8 vf0 = *(const bf16x8*)(vr + ((hi * 16) ^ swv));
      acc[dt] = __builtin_amdgcn_mfma_f32_32x32x16_bf16(vf0, pb0, acc[dt], 0, 0, 0);
      bf16x8 vf1 = *(const bf16x8*)(vr + ((32 + hi * 16) ^ swv));
      acc[dt] = __builtin_amdgcn_mfma_f32_32x32x16_bf16(vf1, pb1, acc[dt], 0, 0, 0);
    }
    __syncthreads();   // b2: Vs readers done; K(kt+1) stage drained
    if (kt + 1 < t1) STAGE_V(kt + 1);   // drained at next b1
  }
  // ---- epilogue: unnormalized partial O + (m,l) stats ----
  u16* Os = sp ? Os1 : Os0;
  u16* orow = Os + (size_t)(b * TT + q0 + l31) * CC + h2 * DD + hi * 4;
#pragma unroll
  for (int dt = 0; dt < 8; ++dt)
#pragma unroll
    for (int rg = 0; rg < 4; ++rg){
      ushort4 pk;
      pk.x = f2bf(acc[dt][rg * 4 + 0]); pk.y = f2bf(acc[dt][rg * 4 + 1]);
      pk.z = f2bf(acc[dt][rg * 4 + 2]); pk.w = f2bf(acc[dt][rg * 4 + 3]);
      *(ushort4*)(orow + dt * 32 + rg * 8) = pk;
    }
  if (lane < 32)
    stats[(size_t)((sp * 16 + bh) << 11) + q0 + l31] = make_float2(mrun, lrun);
#undef STAGE_K
#undef STAGE_V
}

// ---------------- combine the two kv-split partials ----------------
__global__ __launch_bounds__(256) void attn_combine(
    const u16* __restrict__ Os0, const u16* __restrict__ Os1,
    const float2* __restrict__ stats, u16* __restrict__ AO){
  const int row = blockIdx.x, tid = threadIdx.x;
  const int b = row >> 11, q = row & (TT - 1);
  const int h2 = tid >> 6;
  const int bh = b * HH + h2;
  const float2 sA = stats[(size_t)(bh << 11) + q];
  const float2 sB = stats[(size_t)((16 + bh) << 11) + q];
  const float m = fmaxf(sA.x, sB.x);
  const float eA = __builtin_exp2f(sA.x - m), eB = __builtin_exp2f(sB.x - m);
  const float l = sA.y * eA + sB.y * eB;
  const float fA = eA / l, fB = eB / l;
  const size_t off = (size_t)row * CC + tid * 4;
  const ushort4 a = *(const ushort4*)(Os0 + off);
  const ushort4 c = *(const ushort4*)(Os1 + off);
  ushort4 o;
  o.x = f2bf(bf2f(a.x) * fA + bf2f(c.x) * fB);
  o.y = f2bf(bf2f(a.y) * fA + bf2f(c.y) * fB);
  o.z = f2bf(bf2f(a.z) * fA + bf2f(c.z) * fB);
  o.w = f2bf(bf2f(a.w) * fA + bf2f(c.w) * fB);
  *(ushort4*)(AO + off) = o;
}

// ---------------- dwconv(tc) + bias + exact GELU ----------------
__global__ __launch_bounds__(256) void tc_gelu(const u16* __restrict__ y2,
    const float* __restrict__ w, const float* __restrict__ bias, u16* __restrict__ y3){
  const int row = blockIdx.x, tid = threadIdx.x;
  const int t = row & (TT - 1);
  const int c = tid * 4;
  ushort4 z4; z4.x = z4.y = z4.z = z4.w = 0;
  const ushort4 u0 = *(const ushort4*)(y2 + (size_t)row * CC + c);
  const ushort4 um = (t > 0)      ? *(const ushort4*)(y2 + (size_t)(row - 1) * CC + c) : z4;
  const ushort4 up = (t < TT - 1) ? *(const ushort4*)(y2 + (size_t)(row + 1) * CC + c) : z4;
  const float am[4] = {bf2f(um.x), bf2f(um.y), bf2f(um.z), bf2f(um.w)};
  const float a0[4] = {bf2f(u0.x), bf2f(u0.y), bf2f(u0.z), bf2f(u0.w)};
  const float ap[4] = {bf2f(up.x), bf2f(up.y), bf2f(up.z), bf2f(up.w)};
  u16 pv[4];
#pragma unroll
  for (int i = 0; i < 4; ++i){
    const float* wp = w + (c + i) * 3;
    const float yv = am[i] * wp[0] + a0[i] * wp[1] + ap[i] * wp[2] + bias[c + i];
    const float ge = 0.5f * yv * (1.f + erff(yv * 0.7071067811865475f));
    pv[i] = f2bf(ge);
  }
  ushort4 p; p.x = pv[0]; p.y = pv[1]; p.z = pv[2]; p.w = pv[3];
  *(ushort4*)(y3 + (size_t)row * CC + c) = p;
}

extern "C" void kernel_launch(void* const* d_in, const int* in_sizes, int n_in,
                              void* d_out, int out_size, void* d_ws, size_t ws_size,
                              hipStream_t stream){
  const float* x     = (const float*)d_in[0];
  const int*   mask  = (const int*)d_in[1];
  const float* n1g   = (const float*)d_in[2];
  const float* n1b   = (const float*)d_in[3];
  const float* qconv = (const float*)d_in[4];
  const float* kconv = (const float*)d_in[5];
  const float* vconv = (const float*)d_in[6];
  const float* qg    = (const float*)d_in[7];
  const float* qbe   = (const float*)d_in[8];
  const float* kg    = (const float*)d_in[9];
  const float* kbe   = (const float*)d_in[10];
  const float* vg    = (const float*)d_in[11];
  const float* vbe   = (const float*)d_in[12];
  const float* q1w   = (const float*)d_in[13];
  const float* q1b   = (const float*)d_in[14];
  const float* k1w   = (const float*)d_in[15];
  const float* k1b   = (const float*)d_in[16];
  const float* v1w   = (const float*)d_in[17];
  const float* v1b   = (const float*)d_in[18];
  const float* pw    = (const float*)d_in[19];
  const float* pb    = (const float*)d_in[20];
  const float* n2g   = (const float*)d_in[21];
  const float* n2b   = (const float*)d_in[22];
  const float* l1w   = (const float*)d_in[23];
  const float* l1b   = (const float*)d_in[24];
  const float* tcw   = (const float*)d_in[25];
  const float* tcb   = (const float*)d_in[26];
  const float* l2w   = (const float*)d_in[27];
  const float* l2b   = (const float*)d_in[28];
  (void)in_sizes; (void)n_in; (void)out_size; (void)ws_size;

  char* ws = (char*)d_ws;
  const size_t MB = (size_t)1 << 20;
  u16* wq  = (u16*)(ws + 0 * MB);
  u16* wk  = (u16*)(ws + 2 * MB);
  u16* wv  = (u16*)(ws + 4 * MB);
  u16* wp2 = (u16*)(ws + 6 * MB);
  u16* wl1 = (u16*)(ws + 8 * MB);
  u16* wl2 = (u16*)(ws + 10 * MB);
  u16* hbuf = (u16*)(ws + 12 * MB);   // 16 MB bf16 LN1 output; dead after qkv_pre
  u16* x2b  = (u16*)(ws + 12 * MB);   // 16 MB bf16 residual stream; written after hbuf dead
  u16* qn  = (u16*)(ws + 44 * MB);
  u16* kn  = (u16*)(ws + 60 * MB);
  u16* vn  = (u16*)(ws + 76 * MB);
  u16* Qb  = (u16*)(ws + 92 * MB);
  u16* Kb  = (u16*)(ws + 108 * MB);
  u16* Vtb = (u16*)(ws + 124 * MB);
  float2* stats = (float2*)(ws + 140 * MB);   // 512 KB
  u16* AO  = qn;    // attnout  (qn dead after qkv GEMM)
  u16* Os0 = kn;    // kv-split partial 0 (kn dead after qkv GEMM)
  u16* Os1 = vn;    // kv-split partial 1 (vn dead after qkv GEMM)
  u16* y1  = kn;    // LN2 out  (Os0 dead after combine)
  u16* y2  = vn;    // lin1 out (Os1 dead after combine)
  u16* y3  = Qb;    // gelu out (Q dead after flash)

  ln_rows_w<<<MM, 256, 0, stream>>>(x, n1g, n1b, hbuf,
                                    q1w, k1w, v1w, pw, l1w, l2w, wq, wk, wv, wp2, wl1, wl2);
  qkv_pre<<<MM, 256, 0, stream>>>(hbuf, mask, qconv, kconv, vconv,
                                  qg, qbe, kg, kbe, vg, vbe, qn, kn, vn);
  gemm_qkv<<<dim3(64, 8, 3), 256, 0, stream>>>(qn, kn, vn, wq, wk, wv, q1b, k1b, v1b, Qb, Kb, Vtb);
  flash_attn<<<512, 256, 0, stream>>>(Qb, Kb, Vtb, mask, Os0, Os1, stats);
  attn_combine<<<MM, 256, 0, stream>>>(Os0, Os1, stats, AO);
  gemm_bt<1><<<dim3(64, 8), 256, 0, stream>>>(AO, wp2, pb, x2b, x, mask);
  ln_rows_b2b<<<MM, 256, 0, stream>>>(x2b, n2g, n2b, y1);
  gemm_bt<0><<<dim3(64, 8), 256, 0, stream>>>(y1, wl1, l1b, y2, nullptr, nullptr);
  tc_gelu<<<MM, 256, 0, stream>>>(y2, tcw, tcb, y3);
  gemm_bt<2><<<dim3(64, 8), 256, 0, stream>>>(y3, wl2, l2b, (float*)d_out, x2b, nullptr);
}